// Round 11
// baseline (301.323 us; speedup 1.0000x reference)
//
#include <hip/hip_runtime.h>
#include <math.h>

#define EPSF 1e-5f
#define CAP  88        // per-dst edge slots: Poisson(32) + ~10 sigma
#define DBH  7         // log2(dsts per bucket) = 128
#define NB2MAX 1024    // cursor stride (nb2=782 for Nd=100k)
#define SH2  704       // per-(bucket,shard) span cap (fill~512, +8.5 sigma)
#define BK2CAP (8 * SH2)   // 5632 words per bucket region
#define TILE 2048      // edges per scatter_sb2 tile (1563 blocks, ~6/CU)
#define XPADS2 104     // x row stride in ushorts (96 + 8)
#define X2PADS 72      // h1 row stride in shorts (64 + 8)
#define NPACK 14336    // packed bf16 weight elements (Wagg 6144 | W1 6144 | W2 2048)

typedef __attribute__((ext_vector_type(8))) short short8;
typedef __attribute__((ext_vector_type(4))) float float4v;
typedef __attribute__((ext_vector_type(4))) unsigned uint4v;

__device__ inline unsigned f2bf_rne(float x) {
    unsigned u = __float_as_uint(x);
    u += 0x7FFF + ((u >> 16) & 1);
    return u >> 16;
}
__device__ inline short bf16_of(float x) { return (short)f2bf_rne(x); }
__device__ inline float bf2f_lo(unsigned hv) { return __uint_as_float(hv << 16); }
__device__ inline float bf2f_hi(unsigned hv) { return __uint_as_float(hv & 0xFFFF0000u); }
__device__ inline float bf2f_s(ushort s) { return __uint_as_float((unsigned)s << 16); }

// ---- setup: sharded cursor init | pack dense weights | cast w to bf16 -----
// (no deg zeroing: scatter_fine6 writes every deg entry directly)
__global__ __launch_bounds__(256) void setup_all(
    int* sbcursor, int nb2,
    const float* __restrict__ W_agg, const float* __restrict__ W1,
    const float* __restrict__ W2, ushort* __restrict__ wpack,
    const float* __restrict__ w, ushort* __restrict__ wb, int VD, int do_cast)
{
    int bid = blockIdx.x;
    if (bid == 0) {
        for (int j = threadIdx.x; j < 8 * NB2MAX; j += 256) {
            int s = j >> 10;                 // NB2MAX == 1024
            int B = j & (NB2MAX - 1);
            sbcursor[j] = (B < nb2) ? (B * BK2CAP + s * SH2) : 0;
        }
        return;
    }
    if (bid == 1) {
        for (int it = threadIdx.x; it < 1792; it += 256) {
            if (it < 768) {                       // W_agg [2][192][16]
                int t_g = it >> 6; int rem = it & 63;
                int q = rem >> 4, col = rem & 15;
                int kvar = t_g / 6, t = t_g % 6;
                const float* src = W_agg + kvar * 3072 + (t * 32 + q * 8) * 16 + col;
                ushort* dst = wpack + (size_t)it * 8;
#pragma unroll
                for (int j = 0; j < 8; ++j) dst[j] = (ushort)f2bf_rne(src[j * 16]);
            } else if (it < 1536) {               // W1 [96][64]
                int i2 = it - 768;
                int t = i2 >> 8; int rem = i2 & 255;
                int q = rem >> 6, col = rem & 63;
                const float* src = W1 + (t * 32 + q * 8) * 64 + col;
                ushort* dst = wpack + 6144 + (size_t)i2 * 8;
#pragma unroll
                for (int j = 0; j < 8; ++j) dst[j] = (ushort)f2bf_rne(src[j * 64]);
            } else {                              // W2 [64][32]
                int i2 = it - 1536;
                int t = i2 >> 7; int rem = i2 & 127;
                int q = rem >> 5, col = rem & 31;
                const float* src = W2 + (t * 32 + q * 8) * 32 + col;
                ushort* dst = wpack + 12288 + (size_t)i2 * 8;
#pragma unroll
                for (int j = 0; j < 8; ++j) dst[j] = (ushort)f2bf_rne(src[j * 32]);
            }
        }
        return;
    }
    if (!do_cast) return;
    int i4 = ((bid - 2) * 256 + threadIdx.x) * 4;
    if (i4 + 3 < VD) {
        float4 v = *(const float4*)(w + i4);
        ushort4 o;
        o.x = (ushort)f2bf_rne(v.x); o.y = (ushort)f2bf_rne(v.y);
        o.z = (ushort)f2bf_rne(v.z); o.w = (ushort)f2bf_rne(v.w);
        *(ushort4*)(wb + i4) = o;
    } else {
        for (int j = i4; j < VD; ++j) wb[j] = (ushort)f2bf_rne(w[j]);
    }
}

// ------ precompute h_src: one THREAD per source node, wide ld/st -----------
// h[s*16+d] = bf16(mean_f w[cat]) | bf16(max_f w[cat]) << 16
__global__ __launch_bounds__(256) void build_h2(
    const int* __restrict__ Cat_src, const ushort* __restrict__ wb,
    unsigned* __restrict__ h, int Ns)
{
    int s = blockIdx.x * 256 + threadIdx.x;
    if (s >= Ns) return;
    int4 c = *(const int4*)(Cat_src + (size_t)s * 4);
    const short8* r0 = (const short8*)(wb + (size_t)c.x * 16);
    const short8* r1 = (const short8*)(wb + (size_t)c.y * 16);
    const short8* r2 = (const short8*)(wb + (size_t)c.z * 16);
    const short8* r3 = (const short8*)(wb + (size_t)c.w * 16);
    short8 a0 = r0[0], b0 = r0[1];     // 8 independent 16B loads in flight
    short8 a1 = r1[0], b1 = r1[1];
    short8 a2 = r2[0], b2 = r2[1];
    short8 a3 = r3[0], b3 = r3[1];
    uint4v o0, o1, o2, o3;
#pragma unroll
    for (int d = 0; d < 8; ++d) {
        float v0 = bf2f_s((ushort)a0[d]), v1 = bf2f_s((ushort)a1[d]);
        float v2 = bf2f_s((ushort)a2[d]), v3 = bf2f_s((ushort)a3[d]);
        float mean = (v0 + v1 + v2 + v3) * 0.25f;
        float mx = fmaxf(fmaxf(v0, v1), fmaxf(v2, v3));
        unsigned pk = f2bf_rne(mean) | (f2bf_rne(mx) << 16);
        if (d < 4) o0[d] = pk; else o1[d - 4] = pk;
    }
#pragma unroll
    for (int d = 0; d < 8; ++d) {
        float v0 = bf2f_s((ushort)b0[d]), v1 = bf2f_s((ushort)b1[d]);
        float v2 = bf2f_s((ushort)b2[d]), v3 = bf2f_s((ushort)b3[d]);
        float mean = (v0 + v1 + v2 + v3) * 0.25f;
        float mx = fmaxf(fmaxf(v0, v1), fmaxf(v2, v3));
        unsigned pk = f2bf_rne(mean) | (f2bf_rne(mx) << 16);
        if (d < 4) o2[d] = pk; else o3[d - 4] = pk;
    }
    uint4v* hp = (uint4v*)(h + (size_t)s * 16);
    __builtin_nontemporal_store(o0, hp);
    __builtin_nontemporal_store(o1, hp + 1);
    __builtin_nontemporal_store(o2, hp + 2);
    __builtin_nontemporal_store(o3, hp + 3);
}

// ------- pass 1: scatter edges into sharded 128-dst bucket regions ---------
// pair = (src << 7) | (dst & 127); shard = blockIdx&7; batched claims
__global__ __launch_bounds__(256) void scatter_sb2(
    const int* __restrict__ src_ids, const int* __restrict__ dst_ids,
    int* sbcursor, unsigned* __restrict__ pairs1, int E, int nb2)
{
    __shared__ int cnt[NB2MAX];
    __shared__ int base[NB2MAX];
    int tid = threadIdx.x;
    int t0 = blockIdx.x * TILE;
    int shard = blockIdx.x & 7;
    for (int i = tid; i < nb2; i += 256) cnt[i] = 0;
    __syncthreads();
    int dj[2][4];
    int rank[2][4];
#pragma unroll
    for (int j = 0; j < 2; ++j) {
        int e4 = t0 + (j * 256 + tid) * 4;
        if (e4 + 3 < E) {
            int4 dd = *(const int4*)(dst_ids + e4);
            dj[j][0] = dd.x; dj[j][1] = dd.y; dj[j][2] = dd.z; dj[j][3] = dd.w;
#pragma unroll
            for (int k = 0; k < 4; ++k)
                rank[j][k] = atomicAdd(&cnt[dj[j][k] >> DBH], 1);
        } else {
#pragma unroll
            for (int k = 0; k < 4; ++k) {
                int e = e4 + k;
                dj[j][k] = (e < E) ? dst_ids[e] : 0;
                rank[j][k] = (e < E) ? atomicAdd(&cnt[dj[j][k] >> DBH], 1) : 0;
            }
        }
    }
    __syncthreads();
    for (int i = tid; i < nb2; i += 256) {
        int c = cnt[i];
        base[i] = c ? atomicAdd(&sbcursor[shard * NB2MAX + i], c) : 0;
    }
    __syncthreads();
#pragma unroll
    for (int j = 0; j < 2; ++j) {
        int e4 = t0 + (j * 256 + tid) * 4;
        if (e4 + 3 < E) {
            int4 sv = *(const int4*)(src_ids + e4);
            int sj[4] = {sv.x, sv.y, sv.z, sv.w};
#pragma unroll
            for (int k = 0; k < 4; ++k) {
                int d = dj[j][k];
                int bk = d >> DBH;
                int idx = base[bk] + rank[j][k];
                if (idx < bk * BK2CAP + (shard + 1) * SH2)    // shard guard
                    pairs1[idx] = ((unsigned)sj[k] << DBH) | (unsigned)(d & 127);
            }
        } else {
#pragma unroll
            for (int k = 0; k < 4; ++k) {
                int e = e4 + k;
                if (e < E) {
                    int d = dj[j][k];
                    int bk = d >> DBH;
                    int idx = base[bk] + rank[j][k];
                    if (idx < bk * BK2CAP + (shard + 1) * SH2)
                        pairs1[idx] = ((unsigned)src_ids[e] << DBH)
                                    | (unsigned)(d & 127);
                }
            }
        }
    }
}

// ------- pass 2: single-owner deal into per-dst CAP-slot windows -----------
// ONE block per 128-dst bucket: reads its 8 shard spans into fixed register
// slots, ranks via 128 LDS counters, writes each dst window contiguously.
// No global atomics; deg stored directly.
__global__ __launch_bounds__(256) void scatter_fine6(
    const unsigned* __restrict__ pairs1, const int* __restrict__ sbcursor,
    unsigned* __restrict__ pairs2, int* __restrict__ deg, int Nd, int nb2)
{
    __shared__ int cnt[128];
    int B = blockIdx.x;
    if (B >= nb2) return;
    int tid = threadIdx.x;
    if (tid < 128) cnt[tid] = 0;
    __syncthreads();
    unsigned pv[24];
    int rk[24];
#pragma unroll
    for (int s = 0; s < 8; ++s) {
        int sb0 = B * BK2CAP + s * SH2;
        int fill = sbcursor[s * NB2MAX + B] - sb0;
        if (fill > SH2) fill = SH2;
#pragma unroll
        for (int it = 0; it < 3; ++it) {          // SH2=704 -> 3 x 256 covers
            int slot = s * 3 + it;
            int off = it * 256 + tid;
            if (off < fill) {
                unsigned p = __builtin_nontemporal_load(&pairs1[sb0 + off]);
                pv[slot] = p;
                rk[slot] = atomicAdd(&cnt[p & 127u], 1);
            } else {
                rk[slot] = -1;
            }
        }
    }
    // window writes: rank is final order (sole owner) -> contiguous fills
#pragma unroll
    for (int slot = 0; slot < 24; ++slot) {
        int r = rk[slot];
        if (r >= 0 && r < CAP) {
            unsigned p = pv[slot];
            pairs2[(size_t)((B << DBH) + (p & 127u)) * CAP + r] = p >> DBH;
        }
    }
    __syncthreads();
    if (tid < 128) {
        int g = (B << DBH) + tid;
        if (g < Nd) deg[g] = cnt[tid];            // true retained count
    }
}

// ====== shared epilogue: cross-sub reduce + stat select + tmpb write =======
__device__ inline void emit_stats(float sum0, float sq0, float mn0, float mx0,
                                  float sum1, float sq1, float mn1, float mx1,
                                  int dg, int n, int lane, int sub,
                                  ushort* __restrict__ tmpb)
{
#pragma unroll
    for (int off = 16; off <= 32; off <<= 1) {
        sum0 += __shfl_xor(sum0, off); sq0 += __shfl_xor(sq0, off);
        mn0 = fminf(mn0, __shfl_xor(mn0, off)); mx0 = fmaxf(mx0, __shfl_xor(mx0, off));
        sum1 += __shfl_xor(sum1, off); sq1 += __shfl_xor(sq1, off);
        mn1 = fminf(mn1, __shfl_xor(mn1, off)); mx1 = fmaxf(mx1, __shfl_xor(mx1, off));
    }
    float safe = fmaxf((float)dg, 1.f);
    float r = 1.f / safe;
    bool has = dg > 0;
    float mean0 = sum0 * r, mean1 = sum1 * r;
    float sd0 = sqrtf(fmaxf(sq0 * r - mean0 * mean0, 0.f) + EPSF);
    float sd1 = sqrtf(fmaxf(sq1 * r - mean1 * mean1, 0.f) + EPSF);
    float v0 = (sub == 0) ? mean0 : (sub == 1) ? (has ? mn0 : 0.f)
             : (sub == 2) ? (has ? mx0 : 0.f) : sd0;
    float v1 = (sub == 0) ? mean1 : (sub == 1) ? (has ? mn1 : 0.f)
             : (sub == 2) ? (has ? mx1 : 0.f) : sd1;
    ushort* tp = tmpb + (size_t)n * 128;
    tp[lane] = (ushort)f2bf_rne(v0);
    tp[64 + lane] = (ushort)f2bf_rne(v1);
}

// ---- sort-free agg: one wave per dst node, 8 gathers in flight ------------
__global__ __launch_bounds__(256) void agg_from_h2(
    const unsigned* __restrict__ h, const int* __restrict__ deg,
    const unsigned* __restrict__ pairs,
    ushort* __restrict__ tmpb, int Nd)
{
    int tid = threadIdx.x;
    int wv = tid >> 6, lane = tid & 63, sub = lane >> 4, d = lane & 15;
    int n = blockIdx.x * 4 + wv;
    if (n >= Nd) return;
    int dg = deg[n];
    int dgc = (dg < CAP) ? dg : CAP;
    const unsigned* pw = pairs + (size_t)n * CAP;

    float sum0 = 0.f, sq0 = 0.f, mn0 = INFINITY, mx0 = -INFINITY;
    float sum1 = 0.f, sq1 = 0.f, mn1 = INFINITY, mx1 = -INFINITY;

    int nfull = dgc >> 5;                // full 32-edge blocks: no predication
    for (int t = 0; t < nfull; ++t) {
        const unsigned* pp = pw + t * 32 + sub;
        unsigned pv[8], hv[8];
#pragma unroll
        for (int j = 0; j < 8; ++j) pv[j] = pp[j * 4];
#pragma unroll
        for (int j = 0; j < 8; ++j) hv[j] = h[pv[j] * 16 + d];
#pragma unroll
        for (int j = 0; j < 8; ++j) {
            float me = bf2f_lo(hv[j]);
            float vm = bf2f_hi(hv[j]);
            sum0 += me; sq0 += me * me;
            mn0 = fminf(mn0, me); mx0 = fmaxf(mx0, me);
            sum1 += vm; sq1 += vm * vm;
            mn1 = fminf(mn1, vm); mx1 = fmaxf(mx1, vm);
        }
    }
    int base = nfull << 5;
    int rem = dgc - base;                // tail: 4-granular, clamp-loaded
    if (rem > 0) {
        int last = dgc - 1;
        unsigned pv[8], hv[8];
#pragma unroll
        for (int j = 0; j < 8; ++j) {
            if (j * 4 < rem) {
                int e = base + j * 4 + sub;
                pv[j] = pw[e < last ? e : last];
            }
        }
#pragma unroll
        for (int j = 0; j < 8; ++j)
            if (j * 4 < rem) hv[j] = h[pv[j] * 16 + d];
#pragma unroll
        for (int j = 0; j < 8; ++j) {
            if (j * 4 < rem) {
                if (base + j * 4 + sub < dgc) {
                    float me = bf2f_lo(hv[j]);
                    float vm = bf2f_hi(hv[j]);
                    sum0 += me; sq0 += me * me;
                    mn0 = fminf(mn0, me); mx0 = fmaxf(mx0, me);
                    sum1 += vm; sq1 += vm * vm;
                    mn1 = fminf(mn1, vm); mx1 = fmaxf(mx1, vm);
                }
            }
        }
    }
    emit_stats(sum0, sq0, mn0, mx0, sum1, sq1, mn1, mx1,
               dg, n, lane, sub, tmpb);
}

// ---- fallback (small ws): gather w per edge, per-dst windows --------------
__global__ __launch_bounds__(256) void agg_from_w2(
    const int* __restrict__ Cat_src, const float* __restrict__ w,
    const ushort* __restrict__ wb, int use_bf,
    const int* __restrict__ deg, const unsigned* __restrict__ pairs,
    ushort* __restrict__ tmpb, int Nd)
{
    int tid = threadIdx.x;
    int wv = tid >> 6, lane = tid & 63, sub = lane >> 4, d = lane & 15;
    int n = blockIdx.x * 4 + wv;
    if (n >= Nd) return;
    int dg = deg[n];
    int dgc = (dg < CAP) ? dg : CAP;
    const unsigned* pw = pairs + (size_t)n * CAP;

    float sum0 = 0.f, sq0 = 0.f, mn0 = INFINITY, mx0 = -INFINITY;
    float sum1 = 0.f, sq1 = 0.f, mn1 = INFINITY, mx1 = -INFINITY;
    int nt = (dgc + 3) >> 2;
    for (int t = 0; t < nt; ++t) {
        int e4 = t * 4 + sub;
        int ec = (e4 < dgc) ? e4 : (dgc - 1);
        int src = (dgc > 0) ? (int)pw[ec] : 0;
        int cat = Cat_src[src * 4 + (d & 3)];
        float vs = 0.f, vm = -INFINITY;
        if (use_bf) {
#pragma unroll
            for (int f = 0; f < 4; ++f) {
                int id = __shfl(cat, sub * 16 + f, 64);
                float a = bf2f_s(wb[id * 16 + d]);
                vs += a; vm = fmaxf(vm, a);
            }
        } else {
#pragma unroll
            for (int f = 0; f < 4; ++f) {
                int id = __shfl(cat, sub * 16 + f, 64);
                float a = w[id * 16 + d];
                vs += a; vm = fmaxf(vm, a);
            }
        }
        if (e4 < dgc) {
            float me = vs * 0.25f;
            sum0 += me; sq0 += me * me;
            mn0 = fminf(mn0, me); mx0 = fmaxf(mx0, me);
            sum1 += vm; sq1 += vm * vm;
            mn1 = fminf(mn1, vm); mx1 = fmaxf(mx1, vm);
        }
    }
    emit_stats(sum0, sq0, mn0, mx0, sum1, sq1, mn1, mx1,
               dg, n, lane, sub, tmpb);
}

// ---------------- finalize via MFMA, packed weights, bf16 X buffer ---------
// Layouts (gfx950, verified): A[m=lane&15][k=(lane>>4)*8+j];
// B[k][n=lane&15]; C/D col=lane&15, row=(lane>>4)*4+reg.
__global__ __launch_bounds__(256) void finalize_mfma(
    const int* __restrict__ Cat_dst, const int* __restrict__ label,
    const float* __restrict__ w, const ushort* __restrict__ wpack,
    const float* __restrict__ b_agg,
    const float* __restrict__ w_lin, const float* __restrict__ b_lin,
    const float* __restrict__ b1, const float* __restrict__ b2,
    const float* __restrict__ W3, const float* __restrict__ b3,
    const int* __restrict__ deg_arr, const ushort* __restrict__ tmpb,
    float* __restrict__ out, int Nd)
{
    __shared__ __align__(16) ushort sx[4][16 * XPADS2];  // x, bf16
    __shared__ __align__(16) ushort sx2[4][16 * X2PADS]; // h1, bf16
    __shared__ float sdeep[4][16];

    int tid = threadIdx.x;
    int wv = tid >> 6, lane = tid & 63;
    int q = lane >> 4, m = lane & 15;
    int n0 = (blockIdx.x * 4 + wv) * 16;
    int n = n0 + m;
    int nc = (n < Nd) ? n : (Nd - 1);

    ushort* X = sx[wv];
    ushort* X2 = sx2[wv];

    float fdeg = (float)deg_arr[nc];
    float logd = logf(fdeg + 1.f);
    const float logavg = logf(33.0f);
    float amp = logd / logavg;
    float att = (logd > 0.f) ? (logavg / fmaxf(logd, EPSF)) : 0.f;
    float ampr[4], attr[4];
#pragma unroll
    for (int r = 0; r < 4; ++r) {
        ampr[r] = __shfl(amp, q * 4 + r, 64);
        attr[r] = __shfl(att, q * 4 + r, 64);
    }

    // Phase A: mes = scaled @ W_agg + b_agg, scalers folded post-MFMA
    const ushort* tpn = tmpb + (size_t)nc * 128;
#pragma unroll
    for (int kvar = 0; kvar < 2; ++kvar) {
        short8 af0 = *(const short8*)(tpn + kvar * 64 + q * 8);
        short8 af1 = *(const short8*)(tpn + kvar * 64 + 32 + q * 8);
        float4v aI = {0.f,0.f,0.f,0.f}, aA = {0.f,0.f,0.f,0.f}, aT = {0.f,0.f,0.f,0.f};
#pragma unroll
        for (int sb = 0; sb < 3; ++sb) {
            short8 b0 = *(const short8*)(wpack +
                (size_t)(((kvar * 6 + sb * 2) * 4 + q) * 16 + m) * 8);
            short8 b1v = *(const short8*)(wpack +
                (size_t)(((kvar * 6 + sb * 2 + 1) * 4 + q) * 16 + m) * 8);
            if (sb == 0) {
                aI = __builtin_amdgcn_mfma_f32_16x16x32_bf16(af0, b0, aI, 0, 0, 0);
                aI = __builtin_amdgcn_mfma_f32_16x16x32_bf16(af1, b1v, aI, 0, 0, 0);
            } else if (sb == 1) {
                aA = __builtin_amdgcn_mfma_f32_16x16x32_bf16(af0, b0, aA, 0, 0, 0);
                aA = __builtin_amdgcn_mfma_f32_16x16x32_bf16(af1, b1v, aA, 0, 0, 0);
            } else {
                aT = __builtin_amdgcn_mfma_f32_16x16x32_bf16(af0, b0, aT, 0, 0, 0);
                aT = __builtin_amdgcn_mfma_f32_16x16x32_bf16(af1, b1v, aT, 0, 0, 0);
            }
        }
        float bias = b_agg[kvar * 16 + m];
#pragma unroll
        for (int r = 0; r < 4; ++r)
            X[(q * 4 + r) * XPADS2 + 64 + kvar * 16 + m] = (ushort)f2bf_rne(
                aI[r] + ampr[r] * aA[r] + attr[r] * aT[r] + bias);
    }
    // Phase B: dst cat embeddings -> X cols 0..63 (bf16)
    {
        int nl = lane >> 2, fl = lane & 3;
        int nn = n0 + nl;
        int nnc = (nn < Nd) ? nn : (Nd - 1);
        int cid = Cat_dst[nnc * 4 + fl];
        const float4* R = (const float4*)(w + (size_t)cid * 16);
        float4 r0 = R[0], r1 = R[1], r2 = R[2], r3 = R[3];
        short8 o0, o1;
        o0[0] = bf16_of(r0.x); o0[1] = bf16_of(r0.y);
        o0[2] = bf16_of(r0.z); o0[3] = bf16_of(r0.w);
        o0[4] = bf16_of(r1.x); o0[5] = bf16_of(r1.y);
        o0[6] = bf16_of(r1.z); o0[7] = bf16_of(r1.w);
        o1[0] = bf16_of(r2.x); o1[1] = bf16_of(r2.y);
        o1[2] = bf16_of(r2.z); o1[3] = bf16_of(r2.w);
        o1[4] = bf16_of(r3.x); o1[5] = bf16_of(r3.y);
        o1[6] = bf16_of(r3.z); o1[7] = bf16_of(r3.w);
        ushort* xp = X + nl * XPADS2 + fl * 16;
        *(short8*)(xp) = o0;
        *(short8*)(xp + 8) = o1;
    }
    __syncthreads();

    // Phase D: lin / FM stats for node m (q splits the 6 fields)
    float lin = 0.f, sq = 0.f;
    float sd[16];
#pragma unroll
    for (int u = 0; u < 16; ++u) sd[u] = 0.f;
    {
        const ushort* xp = X + m * XPADS2 + q * 16;
        const float* wl = w_lin + q * 16;
#pragma unroll
        for (int u = 0; u < 16; ++u) {
            float v = bf2f_s(xp[u]);
            lin += v * wl[u]; sq += v * v; sd[u] += v;
        }
    }
    if (q < 2) {
        const ushort* xp = X + m * XPADS2 + (4 + q) * 16;
        const float* wl = w_lin + (4 + q) * 16;
#pragma unroll
        for (int u = 0; u < 16; ++u) {
            float v = bf2f_s(xp[u]);
            lin += v * wl[u]; sq += v * v; sd[u] += v;
        }
    }
#pragma unroll
    for (int off = 16; off <= 32; off <<= 1) {
        lin += __shfl_xor(lin, off);
        sq  += __shfl_xor(sq, off);
#pragma unroll
        for (int u = 0; u < 16; ++u) sd[u] += __shfl_xor(sd[u], off);
    }
    float fm = 0.f;
#pragma unroll
    for (int u = 0; u < 16; ++u) fm += sd[u] * sd[u];
    fm = 0.5f * (fm - sq);

    // Phase E: h1 = relu(x @ W1 + b1), A-frags direct from bf16 X
    short8 xa[3];
#pragma unroll
    for (int t = 0; t < 3; ++t)
        xa[t] = *(const short8*)(X + m * XPADS2 + t * 32 + q * 8);
#pragma unroll
    for (int nt = 0; nt < 4; ++nt) {
        float4v acc = {0.f, 0.f, 0.f, 0.f};
#pragma unroll
        for (int t = 0; t < 3; ++t) {
            short8 bf = *(const short8*)(wpack + 6144 +
                (size_t)((t * 4 + q) * 64 + nt * 16 + m) * 8);
            acc = __builtin_amdgcn_mfma_f32_16x16x32_bf16(xa[t], bf, acc, 0, 0, 0);
        }
        float bb = b1[nt * 16 + m];
#pragma unroll
        for (int r = 0; r < 4; ++r)
            X2[(q * 4 + r) * X2PADS + nt * 16 + m] =
                (ushort)f2bf_rne(fmaxf(acc[r] + bb, 0.f));
    }
    __syncthreads();

    // Phase F: h2 = relu(h1 @ W2 + b2); deep = h2 @ W3
    short8 ha[2];
#pragma unroll
    for (int t = 0; t < 2; ++t)
        ha[t] = *(const short8*)(X2 + m * X2PADS + t * 32 + q * 8);
    float dp[4] = {0.f, 0.f, 0.f, 0.f};
#pragma unroll
    for (int nt = 0; nt < 2; ++nt) {
        float4v acc = {0.f, 0.f, 0.f, 0.f};
#pragma unroll
        for (int t = 0; t < 2; ++t) {
            short8 bf = *(const short8*)(wpack + 12288 +
                (size_t)((t * 4 + q) * 32 + nt * 16 + m) * 8);
            acc = __builtin_amdgcn_mfma_f32_16x16x32_bf16(ha[t], bf, acc, 0, 0, 0);
        }
        float bb = b2[nt * 16 + m];
        float w3 = W3[nt * 16 + m];
#pragma unroll
        for (int r = 0; r < 4; ++r)
            dp[r] += fmaxf(acc[r] + bb, 0.f) * w3;
    }
#pragma unroll
    for (int off = 1; off <= 8; off <<= 1) {
#pragma unroll
        for (int r = 0; r < 4; ++r) dp[r] += __shfl_xor(dp[r], off);
    }
    if (m < 4)
        sdeep[wv][q * 4 + m] = (m == 0) ? dp[0] : (m == 1) ? dp[1]
                             : (m == 2) ? dp[2] : dp[3];
    __syncthreads();
    float deep = sdeep[wv][m];

    if (q == 0 && n < Nd) {
        float z = lin + b_lin[0] + fm + deep + b3[0];
        float pred = 1.f / (1.f + expf(-z));
        out[n] = pred;
        out[Nd + n] = (float)label[n];
    }
}

extern "C" void kernel_launch(void* const* d_in, const int* in_sizes, int n_in,
                              void* d_out, int out_size, void* d_ws, size_t ws_size,
                              hipStream_t stream) {
    const int*   Cat_src = (const int*)d_in[0];
    const int*   Cat_dst = (const int*)d_in[1];
    const int*   src_ids = (const int*)d_in[2];
    const int*   dst_ids = (const int*)d_in[3];
    const int*   label   = (const int*)d_in[4];
    const float* w       = (const float*)d_in[5];
    const float* W_agg   = (const float*)d_in[6];
    const float* b_agg   = (const float*)d_in[7];
    const float* w_lin   = (const float*)d_in[8];
    const float* b_lin   = (const float*)d_in[9];
    const float* W1      = (const float*)d_in[10];
    const float* b1      = (const float*)d_in[11];
    const float* W2      = (const float*)d_in[12];
    const float* b2      = (const float*)d_in[13];
    const float* W3      = (const float*)d_in[14];
    const float* b3      = (const float*)d_in[15];

    int E  = in_sizes[2];
    int Nd = in_sizes[4];
    int Ns = in_sizes[0] / 4;
    int VD = in_sizes[5];
    int nb2 = (Nd + 127) >> DBH;                // 128-dst buckets; 100k -> 782

    // ws layout: sbcursor[8*NB2MAX] | deg[Nd] | pairs2[Nd*CAP]
    //            | union{ pairs1[nb2*BK2CAP] , tmpb[Nd*128 us] }  (pairs1 dead
    //              after scatter_fine6; tmpb written by agg afterwards)
    //            | wpack[NPACK us] | w_bf16[VD us] | h[Ns*16 u32]
    int* sbcursor = (int*)d_ws;
    int* deg      = sbcursor + 8 * NB2MAX;
    size_t off_p2 = (((size_t)(8 * NB2MAX + Nd)) * 4 + 255) & ~(size_t)255;
    unsigned* pairs2 = (unsigned*)((char*)d_ws + off_p2);
    size_t off_u = (off_p2 + (size_t)Nd * CAP * 4 + 255) & ~(size_t)255;
    unsigned* pairs1 = (unsigned*)((char*)d_ws + off_u);
    ushort*   tmpb   = (ushort*)((char*)d_ws + off_u);
    size_t u_p1 = (size_t)nb2 * BK2CAP * 4;
    size_t u_tm = (size_t)Nd * 256;
    size_t u_bytes = (u_p1 > u_tm) ? u_p1 : u_tm;
    size_t off_w = (off_u + u_bytes + 255) & ~(size_t)255;
    ushort* wpack  = (ushort*)((char*)d_ws + off_w);
    ushort* w_bf16 = wpack + NPACK;
    unsigned* h    = (unsigned*)(w_bf16 + VD);

    size_t need_common = off_w + (size_t)NPACK * 2;
    size_t need_A = need_common + (size_t)VD * 2;
    size_t need_B = need_A + (size_t)Ns * 64;
    int mode = (ws_size >= need_B) ? 2 : (ws_size >= need_A) ? 1 : 0;

    float* out = (float*)d_out;

    int ncb = (mode >= 1) ? (VD / 4 + 255) / 256 : 0;
    hipLaunchKernelGGL(setup_all, dim3(2 + ncb), dim3(256), 0, stream,
                       sbcursor, nb2, W_agg, W1, W2, wpack, w, w_bf16, VD,
                       mode >= 1);
    if (mode == 2) {
        int hb = (Ns + 255) / 256;
        hipLaunchKernelGGL(build_h2, dim3(hb), dim3(256), 0, stream,
                           Cat_src, w_bf16, h, Ns);
    }
    hipLaunchKernelGGL(scatter_sb2, dim3((E + TILE - 1) / TILE), dim3(256), 0, stream,
                       src_ids, dst_ids, sbcursor, pairs1, E, nb2);
    hipLaunchKernelGGL(scatter_fine6, dim3(nb2), dim3(256), 0, stream,
                       pairs1, sbcursor, pairs2, deg, Nd, nb2);
    int nab = (Nd + 3) >> 2;
    if (mode == 2) {
        hipLaunchKernelGGL(agg_from_h2, dim3(nab), dim3(256), 0, stream,
                           h, deg, pairs2, tmpb, Nd);
    } else {
        hipLaunchKernelGGL(agg_from_w2, dim3(nab), dim3(256), 0, stream,
                           Cat_src, w, w_bf16, mode, deg, pairs2, tmpb, Nd);
    }
    hipLaunchKernelGGL(finalize_mfma, dim3((Nd + 63) / 64), dim3(256), 0, stream,
                       Cat_dst, label, w, wpack, b_agg, w_lin, b_lin,
                       b1, b2, W3, b3, deg, tmpb, out, Nd);
}

// Round 12
// 288.196 us; speedup vs baseline: 1.0455x; 1.0455x over previous
//
#include <hip/hip_runtime.h>
#include <math.h>

#define EPSF 1e-5f
#define BSH  5         // log2(fine bucket size in dst nodes)
#define BSZ  32        // dst nodes per fine bucket
#define MAXB 4096      // max fine buckets (Nd/32); Nd=100k -> 3125
#define SBH  9         // log2(superbucket size) = 512 dst nodes
#define MAXSB 256      // max superbuckets; Nd=100k -> 196
#define TILE 2048      // edges per scatter_sb tile (1563 blocks, ~6/CU)
#define SEG  8         // segments per superbucket = cursor shards
#define BCAP 1472      // fine bucket capacity (avg 1024, +14 sigma)
#define SBCAP (16 * BCAP)  // superbucket capacity
#define SHCAP (SBCAP / 8)  // per-shard superbucket span (2944; fill~2054,+19s)
#define CAPW 88        // per-dst LDS row capacity (Poisson(32) + ~10 sigma)
#define XPADS2 104     // x row stride in ushorts (96 + 8)
#define X2PADS 72      // h1 row stride in shorts (64 + 8)
#define NPACK 14336    // packed bf16 weight elements (Wagg 6144 | W1 6144 | W2 2048)

typedef __attribute__((ext_vector_type(8))) short short8;
typedef __attribute__((ext_vector_type(4))) float float4v;
typedef __attribute__((ext_vector_type(4))) unsigned uint4v;

__device__ inline unsigned f2bf_rne(float x) {
    unsigned u = __float_as_uint(x);
    u += 0x7FFF + ((u >> 16) & 1);
    return u >> 16;
}
__device__ inline short bf16_of(float x) { return (short)f2bf_rne(x); }
__device__ inline float bf2f_lo(unsigned hv) { return __uint_as_float(hv << 16); }
__device__ inline float bf2f_hi(unsigned hv) { return __uint_as_float(hv & 0xFFFF0000u); }
__device__ inline float bf2f_s(ushort s) { return __uint_as_float((unsigned)s << 16); }

// ---- setup: strided cursor init | pack dense weights | cast w to bf16 -----
__global__ __launch_bounds__(256) void setup_all(
    int* sbcursor, int* gcur, int nb, int nsb,
    const float* __restrict__ W_agg, const float* __restrict__ W1,
    const float* __restrict__ W2, ushort* __restrict__ wpack,
    const float* __restrict__ w, ushort* __restrict__ wb, int VD, int do_cast)
{
    int nzc = (nb + 255) >> 8;
    int bid = blockIdx.x;
    if (bid < nzc) {
        int i = bid * 256 + threadIdx.x;
        if (i < nb) gcur[i] = i * BCAP;
        if (i < 8 * MAXSB) {                 // sharded cursors [shard][sb]
            int s = i >> 8;                  // MAXSB == 256
            int sb = i & (MAXSB - 1);
            sbcursor[i] = sb * SBCAP + s * SHCAP;
        }
        return;
    }
    if (bid == nzc) {
        for (int it = threadIdx.x; it < 1792; it += 256) {
            if (it < 768) {                       // W_agg [2][192][16]
                int t_g = it >> 6; int rem = it & 63;
                int q = rem >> 4, col = rem & 15;
                int kvar = t_g / 6, t = t_g % 6;
                const float* src = W_agg + kvar * 3072 + (t * 32 + q * 8) * 16 + col;
                ushort* dst = wpack + (size_t)it * 8;
#pragma unroll
                for (int j = 0; j < 8; ++j) dst[j] = (ushort)f2bf_rne(src[j * 16]);
            } else if (it < 1536) {               // W1 [96][64]
                int i2 = it - 768;
                int t = i2 >> 8; int rem = i2 & 255;
                int q = rem >> 6, col = rem & 63;
                const float* src = W1 + (t * 32 + q * 8) * 64 + col;
                ushort* dst = wpack + 6144 + (size_t)i2 * 8;
#pragma unroll
                for (int j = 0; j < 8; ++j) dst[j] = (ushort)f2bf_rne(src[j * 64]);
            } else {                              // W2 [64][32]
                int i2 = it - 1536;
                int t = i2 >> 7; int rem = i2 & 127;
                int q = rem >> 5, col = rem & 31;
                const float* src = W2 + (t * 32 + q * 8) * 32 + col;
                ushort* dst = wpack + 12288 + (size_t)i2 * 8;
#pragma unroll
                for (int j = 0; j < 8; ++j) dst[j] = (ushort)f2bf_rne(src[j * 32]);
            }
        }
        return;
    }
    if (!do_cast) return;
    int i4 = ((bid - nzc - 1) * 256 + threadIdx.x) * 4;
    if (i4 + 3 < VD) {
        float4 v = *(const float4*)(w + i4);
        ushort4 o;
        o.x = (ushort)f2bf_rne(v.x); o.y = (ushort)f2bf_rne(v.y);
        o.z = (ushort)f2bf_rne(v.z); o.w = (ushort)f2bf_rne(v.w);
        *(ushort4*)(wb + i4) = o;
    } else {
        for (int j = i4; j < VD; ++j) wb[j] = (ushort)f2bf_rne(w[j]);
    }
}

// ------ precompute h_src: one THREAD per source node, wide ld/st -----------
// h[s*16+d] = bf16(mean_f w[cat]) | bf16(max_f w[cat]) << 16
__global__ __launch_bounds__(256) void build_h2(
    const int* __restrict__ Cat_src, const ushort* __restrict__ wb,
    unsigned* __restrict__ h, int Ns)
{
    int s = blockIdx.x * 256 + threadIdx.x;
    if (s >= Ns) return;
    int4 c = *(const int4*)(Cat_src + (size_t)s * 4);
    const short8* r0 = (const short8*)(wb + (size_t)c.x * 16);
    const short8* r1 = (const short8*)(wb + (size_t)c.y * 16);
    const short8* r2 = (const short8*)(wb + (size_t)c.z * 16);
    const short8* r3 = (const short8*)(wb + (size_t)c.w * 16);
    short8 a0 = r0[0], b0 = r0[1];     // 8 independent 16B loads in flight
    short8 a1 = r1[0], b1 = r1[1];
    short8 a2 = r2[0], b2 = r2[1];
    short8 a3 = r3[0], b3 = r3[1];
    uint4v o0, o1, o2, o3;
#pragma unroll
    for (int d = 0; d < 8; ++d) {
        float v0 = bf2f_s((ushort)a0[d]), v1 = bf2f_s((ushort)a1[d]);
        float v2 = bf2f_s((ushort)a2[d]), v3 = bf2f_s((ushort)a3[d]);
        float mean = (v0 + v1 + v2 + v3) * 0.25f;
        float mx = fmaxf(fmaxf(v0, v1), fmaxf(v2, v3));
        unsigned pk = f2bf_rne(mean) | (f2bf_rne(mx) << 16);
        if (d < 4) o0[d] = pk; else o1[d - 4] = pk;
    }
#pragma unroll
    for (int d = 0; d < 8; ++d) {
        float v0 = bf2f_s((ushort)b0[d]), v1 = bf2f_s((ushort)b1[d]);
        float v2 = bf2f_s((ushort)b2[d]), v3 = bf2f_s((ushort)b3[d]);
        float mean = (v0 + v1 + v2 + v3) * 0.25f;
        float mx = fmaxf(fmaxf(v0, v1), fmaxf(v2, v3));
        unsigned pk = f2bf_rne(mean) | (f2bf_rne(mx) << 16);
        if (d < 4) o2[d] = pk; else o3[d - 4] = pk;
    }
    uint4v* hp = (uint4v*)(h + (size_t)s * 16);
    __builtin_nontemporal_store(o0, hp);
    __builtin_nontemporal_store(o1, hp + 1);
    __builtin_nontemporal_store(o2, hp + 2);
    __builtin_nontemporal_store(o3, hp + 3);
}

// ------- pass 1: scatter edges into sharded superbucket regions ------------
// pair = (src << 9) | (dst & 511); shard = blockIdx&7
__global__ __launch_bounds__(256) void scatter_sb(
    const int* __restrict__ src_ids, const int* __restrict__ dst_ids,
    int* sbcursor, unsigned* __restrict__ pairs1, int E, int nsb)
{
    __shared__ int cnt[MAXSB];
    __shared__ int base[MAXSB];
    int tid = threadIdx.x;
    int t0 = blockIdx.x * TILE;
    int shard = blockIdx.x & 7;
    for (int i = tid; i < nsb; i += 256) cnt[i] = 0;
    __syncthreads();
    int dj[2][4];
    int rank[2][4];
#pragma unroll
    for (int j = 0; j < 2; ++j) {
        int e4 = t0 + (j * 256 + tid) * 4;
        if (e4 + 3 < E) {
            int4 dd = *(const int4*)(dst_ids + e4);
            dj[j][0] = dd.x; dj[j][1] = dd.y; dj[j][2] = dd.z; dj[j][3] = dd.w;
#pragma unroll
            for (int k = 0; k < 4; ++k)
                rank[j][k] = atomicAdd(&cnt[dj[j][k] >> SBH], 1);
        } else {
#pragma unroll
            for (int k = 0; k < 4; ++k) {
                int e = e4 + k;
                dj[j][k] = (e < E) ? dst_ids[e] : 0;
                rank[j][k] = (e < E) ? atomicAdd(&cnt[dj[j][k] >> SBH], 1) : 0;
            }
        }
    }
    __syncthreads();
    for (int i = tid; i < nsb; i += 256) {
        int c = cnt[i];
        base[i] = c ? atomicAdd(&sbcursor[shard * MAXSB + i], c) : 0;
    }
    __syncthreads();
#pragma unroll
    for (int j = 0; j < 2; ++j) {
        int e4 = t0 + (j * 256 + tid) * 4;
        if (e4 + 3 < E) {
            int4 sv = *(const int4*)(src_ids + e4);
            int sj[4] = {sv.x, sv.y, sv.z, sv.w};
#pragma unroll
            for (int k = 0; k < 4; ++k) {
                int d = dj[j][k];
                int sb = d >> SBH;
                int idx = base[sb] + rank[j][k];
                if (idx < sb * SBCAP + (shard + 1) * SHCAP)   // shard guard
                    pairs1[idx] = ((unsigned)sj[k] << 9) | (unsigned)(d & 511);
            }
        } else {
#pragma unroll
            for (int k = 0; k < 4; ++k) {
                int e = e4 + k;
                if (e < E) {
                    int d = dj[j][k];
                    int sb = d >> SBH;
                    int idx = base[sb] + rank[j][k];
                    if (idx < sb * SBCAP + (shard + 1) * SHCAP)
                        pairs1[idx] = ((unsigned)src_ids[e] << 9)
                                    | (unsigned)(d & 511);
                }
            }
        }
    }
}

// ------- pass 2: per-shard deal to fixed-capacity fine buckets -------------
// seg == shard: each segment block consumes its shard's span of the SB
__global__ __launch_bounds__(256) void scatter_fine(
    const unsigned* __restrict__ pairs1, const int* __restrict__ sbcursor,
    int* gcur, unsigned* __restrict__ pairs2, int nb, int nsb)
{
    __shared__ int cnt[16];
    __shared__ int base[16];
    int S = blockIdx.x >> 3, seg = blockIdx.x & (SEG - 1);
    int tid = threadIdx.x;
    int s0 = S * SBCAP + seg * SHCAP;
    int s1 = sbcursor[seg * MAXSB + S];          // shard cursor after pass 1
    if (s1 > s0 + SHCAP) s1 = s0 + SHCAP;
    if (tid < 16) cnt[tid] = 0;
    __syncthreads();
    int rank[12];
    unsigned pv[12];
    int nit = (s1 - s0 + 255) >> 8;
    if (nit > 12) nit = 12;          // SHCAP=2944 -> nit <= 12 structurally
    for (int j = 0; j < nit; ++j) {
        int e = s0 + j * 256 + tid;
        if (e < s1) {
            unsigned p = __builtin_nontemporal_load(&pairs1[e]);
            pv[j] = p;
            rank[j] = atomicAdd(&cnt[(p >> 5) & 15], 1);
        }
    }
    __syncthreads();
    if (tid < 16) {
        int gb = (S << 4) + tid;
        int c = cnt[tid];
        base[tid] = (c && gb < nb) ? atomicAdd(&gcur[gb], c) : 0;
    }
    __syncthreads();
    for (int j = 0; j < nit; ++j) {
        int e = s0 + j * 256 + tid;
        if (e < s1) {
            unsigned p = pv[j];
            int fb = (p >> 5) & 15;
            int gb = (S << 4) + fb;
            int idx = base[fb] + rank[j];
            if (idx < (gb + 1) * BCAP)           // capacity guard
                pairs2[idx] = p;
        }
    }
}

// ====== shared helpers =====================================================

__device__ inline void bucket_sort(const unsigned* __restrict__ pairs,
                                   int gbase, int cnt,
                                   unsigned* sp, int* hist, int* ofs, int* start,
                                   int tid)
{
    if (tid < BSZ) hist[tid] = 0;
    __syncthreads();
    for (int i = tid; i < cnt; i += 256)
        atomicAdd(&hist[__builtin_nontemporal_load(&pairs[gbase + i]) & (BSZ - 1)], 1);
    __syncthreads();
    if (tid < BSZ) ofs[tid] = hist[tid];
    __syncthreads();
    for (int off = 1; off < BSZ; off <<= 1) {
        int y = (tid < BSZ && tid >= off) ? ofs[tid - off] : 0;
        __syncthreads();
        if (tid < BSZ) ofs[tid] += y;
        __syncthreads();
    }
    if (tid < BSZ) {
        start[tid] = ofs[tid] - hist[tid];
        ofs[tid] = ofs[tid] - hist[tid];
    }
    __syncthreads();
    for (int i = tid; i < cnt; i += 256) {
        unsigned p = __builtin_nontemporal_load(&pairs[gbase + i]);
        int r = atomicAdd(&ofs[p & (BSZ - 1)], 1);
        sp[r] = p;
    }
    __syncthreads();
}

__device__ inline void emit_stats(float sum0, float sq0, float mn0, float mx0,
                                  float sum1, float sq1, float mn1, float mx1,
                                  int dg, int n, int lane, int sub,
                                  ushort* __restrict__ tmpb, int* __restrict__ deg_out)
{
#pragma unroll
    for (int off = 16; off <= 32; off <<= 1) {
        sum0 += __shfl_xor(sum0, off); sq0 += __shfl_xor(sq0, off);
        mn0 = fminf(mn0, __shfl_xor(mn0, off)); mx0 = fmaxf(mx0, __shfl_xor(mx0, off));
        sum1 += __shfl_xor(sum1, off); sq1 += __shfl_xor(sq1, off);
        mn1 = fminf(mn1, __shfl_xor(mn1, off)); mx1 = fmaxf(mx1, __shfl_xor(mx1, off));
    }
    float safe = fmaxf((float)dg, 1.f);
    float r = 1.f / safe;
    bool has = dg > 0;
    float mean0 = sum0 * r, mean1 = sum1 * r;
    float sd0 = sqrtf(fmaxf(sq0 * r - mean0 * mean0, 0.f) + EPSF);
    float sd1 = sqrtf(fmaxf(sq1 * r - mean1 * mean1, 0.f) + EPSF);
    float v0 = (sub == 0) ? mean0 : (sub == 1) ? (has ? mn0 : 0.f)
             : (sub == 2) ? (has ? mx0 : 0.f) : sd0;
    float v1 = (sub == 0) ? mean1 : (sub == 1) ? (has ? mn1 : 0.f)
             : (sub == 2) ? (has ? mx1 : 0.f) : sd1;
    ushort* tp = tmpb + (size_t)n * 128;
    tp[lane] = (ushort)f2bf_rne(v0);
    tp[64 + lane] = (ushort)f2bf_rne(v1);
    if (lane == 0) deg_out[n] = dg;
}

// ---- gather from packed h; single-pass LDS deal replaces 3-pass sort ------
// sp is [32][88] per-dst rows: one LDS atomic + one LDS store per edge,
// 2 barriers total (vs count + 6-barrier scan + scatter).
__global__ __launch_bounds__(256) void agg_from_h3(
    const unsigned* __restrict__ h, const int* __restrict__ gcur,
    const unsigned* __restrict__ pairs,
    ushort* __restrict__ tmpb, int* __restrict__ deg_out, int Nd)
{
    __shared__ unsigned sp[BSZ * CAPW];    // 11264 B
    __shared__ int cnt[BSZ];
    int b = blockIdx.x, tid = threadIdx.x;
    int gbase = b * BCAP;
    int ecnt = gcur[b] - gbase;
    if (ecnt > BCAP) ecnt = BCAP;
    if (ecnt < 0) ecnt = 0;
    if (tid < BSZ) cnt[tid] = 0;
    __syncthreads();
    for (int i = tid; i < ecnt; i += 256) {
        unsigned p = __builtin_nontemporal_load(&pairs[gbase + i]);
        int dl = (int)(p & (BSZ - 1));
        int r = atomicAdd(&cnt[dl], 1);
        if (r < CAPW) sp[dl * CAPW + r] = p;   // per-dst cap: ~10 sigma guard
    }
    __syncthreads();

    int wv = tid >> 6, lane = tid & 63, sub = lane >> 4, d = lane & 15;
#pragma unroll 1
    for (int q = 0; q < 8; ++q) {
        int dl = wv * 8 + q;
        int n = b * BSZ + dl;
        if (n >= Nd) break;
        int dg = cnt[dl];
        int dgc = (dg < CAPW) ? dg : CAPW;
        const unsigned* swp = sp + dl * CAPW;
        float sum0 = 0.f, sq0 = 0.f, mn0 = INFINITY, mx0 = -INFINITY;
        float sum1 = 0.f, sq1 = 0.f, mn1 = INFINITY, mx1 = -INFINITY;
        int nt = (dgc + 31) >> 5;          // 32 edges per wave-iteration
        for (int t = 0; t < nt; ++t) {
            int base = t * 32 + sub;
            unsigned hv[8];
#pragma unroll
            for (int j = 0; j < 8; ++j) {   // 8 independent gathers in flight
                int e = base + j * 4;
                int ec = (e < dgc) ? e : (dgc - 1);
                unsigned p = swp[ec];
                hv[j] = h[(p >> 9) * 16 + d];
            }
#pragma unroll
            for (int j = 0; j < 8; ++j) {
                int e = base + j * 4;
                if (e < dgc) {
                    float me = bf2f_lo(hv[j]);
                    float vm = bf2f_hi(hv[j]);
                    sum0 += me; sq0 += me * me;
                    mn0 = fminf(mn0, me); mx0 = fmaxf(mx0, me);
                    sum1 += vm; sq1 += vm * vm;
                    mn1 = fminf(mn1, vm); mx1 = fmaxf(mx1, vm);
                }
            }
        }
        emit_stats(sum0, sq0, mn0, mx0, sum1, sq1, mn1, mx1,
                   dg, n, lane, sub, tmpb, deg_out);
    }
}

// ---- fallback: gather w per edge (bf16 table if use_bf, else fp32) --------
__global__ __launch_bounds__(256) void agg_from_w(
    const int* __restrict__ Cat_src, const float* __restrict__ w,
    const ushort* __restrict__ wb, int use_bf, const int* __restrict__ gcur,
    const unsigned* __restrict__ pairs,
    ushort* __restrict__ tmpb, int* __restrict__ deg_out, int Nd)
{
    __shared__ unsigned sp[BCAP];
    __shared__ int hist[BSZ];
    __shared__ int ofs[BSZ];
    __shared__ int start[BSZ];
    int b = blockIdx.x, tid = threadIdx.x;
    int gbase = b * BCAP;
    int cnt = gcur[b] - gbase;
    if (cnt > BCAP) cnt = BCAP;
    if (cnt < 0) cnt = 0;
    bucket_sort(pairs, gbase, cnt, sp, hist, ofs, start, tid);

    int wv = tid >> 6, lane = tid & 63, sub = lane >> 4, d = lane & 15;
#pragma unroll 1
    for (int q = 0; q < 8; ++q) {
        int dl = wv * 8 + q;
        int n = b * BSZ + dl;
        if (n >= Nd) break;
        int st = start[dl], dg = hist[dl];
        float sum0 = 0.f, sq0 = 0.f, mn0 = INFINITY, mx0 = -INFINITY;
        float sum1 = 0.f, sq1 = 0.f, mn1 = INFINITY, mx1 = -INFINITY;
        int nt = (dg + 3) >> 2;
        for (int t = 0; t < nt; ++t) {
            int e4 = t * 4 + sub;
            int ec = (e4 < dg) ? e4 : (dg - 1);
            unsigned p = sp[st + ec];
            int src = (int)(p >> 9);
            int cat = Cat_src[src * 4 + (d & 3)];
            float vs = 0.f, vm = -INFINITY;
            if (use_bf) {
#pragma unroll
                for (int f = 0; f < 4; ++f) {
                    int id = __shfl(cat, sub * 16 + f, 64);
                    float a = bf2f_s(wb[id * 16 + d]);
                    vs += a; vm = fmaxf(vm, a);
                }
            } else {
#pragma unroll
                for (int f = 0; f < 4; ++f) {
                    int id = __shfl(cat, sub * 16 + f, 64);
                    float a = w[id * 16 + d];
                    vs += a; vm = fmaxf(vm, a);
                }
            }
            if (e4 < dg) {
                float me = vs * 0.25f;
                sum0 += me; sq0 += me * me;
                mn0 = fminf(mn0, me); mx0 = fmaxf(mx0, me);
                sum1 += vm; sq1 += vm * vm;
                mn1 = fminf(mn1, vm); mx1 = fmaxf(mx1, vm);
            }
        }
        emit_stats(sum0, sq0, mn0, mx0, sum1, sq1, mn1, mx1,
                   dg, n, lane, sub, tmpb, deg_out);
    }
}

// ---------------- finalize via MFMA, packed weights, bf16 X buffer ---------
// Layouts (gfx950, verified): A[m=lane&15][k=(lane>>4)*8+j];
// B[k][n=lane&15]; C/D col=lane&15, row=(lane>>4)*4+reg.
__global__ __launch_bounds__(256) void finalize_mfma(
    const int* __restrict__ Cat_dst, const int* __restrict__ label,
    const float* __restrict__ w, const ushort* __restrict__ wpack,
    const float* __restrict__ b_agg,
    const float* __restrict__ w_lin, const float* __restrict__ b_lin,
    const float* __restrict__ b1, const float* __restrict__ b2,
    const float* __restrict__ W3, const float* __restrict__ b3,
    const int* __restrict__ deg_arr, const ushort* __restrict__ tmpb,
    float* __restrict__ out, int Nd)
{
    __shared__ __align__(16) ushort sx[4][16 * XPADS2];  // x, bf16
    __shared__ __align__(16) ushort sx2[4][16 * X2PADS]; // h1, bf16
    __shared__ float sdeep[4][16];

    int tid = threadIdx.x;
    int wv = tid >> 6, lane = tid & 63;
    int q = lane >> 4, m = lane & 15;
    int n0 = (blockIdx.x * 4 + wv) * 16;
    int n = n0 + m;
    int nc = (n < Nd) ? n : (Nd - 1);

    ushort* X = sx[wv];
    ushort* X2 = sx2[wv];

    float fdeg = (float)deg_arr[nc];
    float logd = logf(fdeg + 1.f);
    const float logavg = logf(33.0f);
    float amp = logd / logavg;
    float att = (logd > 0.f) ? (logavg / fmaxf(logd, EPSF)) : 0.f;
    float ampr[4], attr[4];
#pragma unroll
    for (int r = 0; r < 4; ++r) {
        ampr[r] = __shfl(amp, q * 4 + r, 64);
        attr[r] = __shfl(att, q * 4 + r, 64);
    }

    // Phase A: mes = scaled @ W_agg + b_agg, scalers folded post-MFMA
    const ushort* tpn = tmpb + (size_t)nc * 128;
#pragma unroll
    for (int kvar = 0; kvar < 2; ++kvar) {
        short8 af0 = *(const short8*)(tpn + kvar * 64 + q * 8);
        short8 af1 = *(const short8*)(tpn + kvar * 64 + 32 + q * 8);
        float4v aI = {0.f,0.f,0.f,0.f}, aA = {0.f,0.f,0.f,0.f}, aT = {0.f,0.f,0.f,0.f};
#pragma unroll
        for (int sb = 0; sb < 3; ++sb) {
            short8 b0 = *(const short8*)(wpack +
                (size_t)(((kvar * 6 + sb * 2) * 4 + q) * 16 + m) * 8);
            short8 b1v = *(const short8*)(wpack +
                (size_t)(((kvar * 6 + sb * 2 + 1) * 4 + q) * 16 + m) * 8);
            if (sb == 0) {
                aI = __builtin_amdgcn_mfma_f32_16x16x32_bf16(af0, b0, aI, 0, 0, 0);
                aI = __builtin_amdgcn_mfma_f32_16x16x32_bf16(af1, b1v, aI, 0, 0, 0);
            } else if (sb == 1) {
                aA = __builtin_amdgcn_mfma_f32_16x16x32_bf16(af0, b0, aA, 0, 0, 0);
                aA = __builtin_amdgcn_mfma_f32_16x16x32_bf16(af1, b1v, aA, 0, 0, 0);
            } else {
                aT = __builtin_amdgcn_mfma_f32_16x16x32_bf16(af0, b0, aT, 0, 0, 0);
                aT = __builtin_amdgcn_mfma_f32_16x16x32_bf16(af1, b1v, aT, 0, 0, 0);
            }
        }
        float bias = b_agg[kvar * 16 + m];
#pragma unroll
        for (int r = 0; r < 4; ++r)
            X[(q * 4 + r) * XPADS2 + 64 + kvar * 16 + m] = (ushort)f2bf_rne(
                aI[r] + ampr[r] * aA[r] + attr[r] * aT[r] + bias);
    }
    // Phase B: dst cat embeddings -> X cols 0..63 (bf16)
    {
        int nl = lane >> 2, fl = lane & 3;
        int nn = n0 + nl;
        int nnc = (nn < Nd) ? nn : (Nd - 1);
        int cid = Cat_dst[nnc * 4 + fl];
        const float4* R = (const float4*)(w + (size_t)cid * 16);
        float4 r0 = R[0], r1 = R[1], r2 = R[2], r3 = R[3];
        short8 o0, o1;
        o0[0] = bf16_of(r0.x); o0[1] = bf16_of(r0.y);
        o0[2] = bf16_of(r0.z); o0[3] = bf16_of(r0.w);
        o0[4] = bf16_of(r1.x); o0[5] = bf16_of(r1.y);
        o0[6] = bf16_of(r1.z); o0[7] = bf16_of(r1.w);
        o1[0] = bf16_of(r2.x); o1[1] = bf16_of(r2.y);
        o1[2] = bf16_of(r2.z); o1[3] = bf16_of(r2.w);
        o1[4] = bf16_of(r3.x); o1[5] = bf16_of(r3.y);
        o1[6] = bf16_of(r3.z); o1[7] = bf16_of(r3.w);
        ushort* xp = X + nl * XPADS2 + fl * 16;
        *(short8*)(xp) = o0;
        *(short8*)(xp + 8) = o1;
    }
    __syncthreads();

    // Phase D: lin / FM stats for node m (q splits the 6 fields)
    float lin = 0.f, sq = 0.f;
    float sd[16];
#pragma unroll
    for (int u = 0; u < 16; ++u) sd[u] = 0.f;
    {
        const ushort* xp = X + m * XPADS2 + q * 16;
        const float* wl = w_lin + q * 16;
#pragma unroll
        for (int u = 0; u < 16; ++u) {
            float v = bf2f_s(xp[u]);
            lin += v * wl[u]; sq += v * v; sd[u] += v;
        }
    }
    if (q < 2) {
        const ushort* xp = X + m * XPADS2 + (4 + q) * 16;
        const float* wl = w_lin + (4 + q) * 16;
#pragma unroll
        for (int u = 0; u < 16; ++u) {
            float v = bf2f_s(xp[u]);
            lin += v * wl[u]; sq += v * v; sd[u] += v;
        }
    }
#pragma unroll
    for (int off = 16; off <= 32; off <<= 1) {
        lin += __shfl_xor(lin, off);
        sq  += __shfl_xor(sq, off);
#pragma unroll
        for (int u = 0; u < 16; ++u) sd[u] += __shfl_xor(sd[u], off);
    }
    float fm = 0.f;
#pragma unroll
    for (int u = 0; u < 16; ++u) fm += sd[u] * sd[u];
    fm = 0.5f * (fm - sq);

    // Phase E: h1 = relu(x @ W1 + b1), A-frags direct from bf16 X
    short8 xa[3];
#pragma unroll
    for (int t = 0; t < 3; ++t)
        xa[t] = *(const short8*)(X + m * XPADS2 + t * 32 + q * 8);
#pragma unroll
    for (int nt = 0; nt < 4; ++nt) {
        float4v acc = {0.f, 0.f, 0.f, 0.f};
#pragma unroll
        for (int t = 0; t < 3; ++t) {
            short8 bf = *(const short8*)(wpack + 6144 +
                (size_t)((t * 4 + q) * 64 + nt * 16 + m) * 8);
            acc = __builtin_amdgcn_mfma_f32_16x16x32_bf16(xa[t], bf, acc, 0, 0, 0);
        }
        float bb = b1[nt * 16 + m];
#pragma unroll
        for (int r = 0; r < 4; ++r)
            X2[(q * 4 + r) * X2PADS + nt * 16 + m] =
                (ushort)f2bf_rne(fmaxf(acc[r] + bb, 0.f));
    }
    __syncthreads();

    // Phase F: h2 = relu(h1 @ W2 + b2); deep = h2 @ W3
    short8 ha[2];
#pragma unroll
    for (int t = 0; t < 2; ++t)
        ha[t] = *(const short8*)(X2 + m * X2PADS + t * 32 + q * 8);
    float dp[4] = {0.f, 0.f, 0.f, 0.f};
#pragma unroll
    for (int nt = 0; nt < 2; ++nt) {
        float4v acc = {0.f, 0.f, 0.f, 0.f};
#pragma unroll
        for (int t = 0; t < 2; ++t) {
            short8 bf = *(const short8*)(wpack + 12288 +
                (size_t)((t * 4 + q) * 32 + nt * 16 + m) * 8);
            acc = __builtin_amdgcn_mfma_f32_16x16x32_bf16(ha[t], bf, acc, 0, 0, 0);
        }
        float bb = b2[nt * 16 + m];
        float w3 = W3[nt * 16 + m];
#pragma unroll
        for (int r = 0; r < 4; ++r)
            dp[r] += fmaxf(acc[r] + bb, 0.f) * w3;
    }
#pragma unroll
    for (int off = 1; off <= 8; off <<= 1) {
#pragma unroll
        for (int r = 0; r < 4; ++r) dp[r] += __shfl_xor(dp[r], off);
    }
    if (m < 4)
        sdeep[wv][q * 4 + m] = (m == 0) ? dp[0] : (m == 1) ? dp[1]
                             : (m == 2) ? dp[2] : dp[3];
    __syncthreads();
    float deep = sdeep[wv][m];

    if (q == 0 && n < Nd) {
        float z = lin + b_lin[0] + fm + deep + b3[0];
        float pred = 1.f / (1.f + expf(-z));
        out[n] = pred;
        out[Nd + n] = (float)label[n];
    }
}

extern "C" void kernel_launch(void* const* d_in, const int* in_sizes, int n_in,
                              void* d_out, int out_size, void* d_ws, size_t ws_size,
                              hipStream_t stream) {
    const int*   Cat_src = (const int*)d_in[0];
    const int*   Cat_dst = (const int*)d_in[1];
    const int*   src_ids = (const int*)d_in[2];
    const int*   dst_ids = (const int*)d_in[3];
    const int*   label   = (const int*)d_in[4];
    const float* w       = (const float*)d_in[5];
    const float* W_agg   = (const float*)d_in[6];
    const float* b_agg   = (const float*)d_in[7];
    const float* w_lin   = (const float*)d_in[8];
    const float* b_lin   = (const float*)d_in[9];
    const float* W1      = (const float*)d_in[10];
    const float* b1      = (const float*)d_in[11];
    const float* W2      = (const float*)d_in[12];
    const float* b2      = (const float*)d_in[13];
    const float* W3      = (const float*)d_in[14];
    const float* b3      = (const float*)d_in[15];

    int E  = in_sizes[2];
    int Nd = in_sizes[4];
    int Ns = in_sizes[0] / 4;
    int VD = in_sizes[5];
    int nb  = (Nd + BSZ - 1) >> BSH;
    int nsb = (nb + 15) >> 4;

    // ws layout: sbcursor[8*MAXSB] | gcur[MAXB] | deg[Nd]
    //            | pairs1[nsb*SBCAP] | pairs2[nb*BCAP] | (align)
    //            | tmpb[Nd*128 us] | wpack[NPACK us] | w_bf16[VD us] | h[Ns*16]
    int* sbcursor = (int*)d_ws;
    int* gcur     = sbcursor + 8 * MAXSB;
    int* deg      = gcur + MAXB;
    unsigned* pairs1 = (unsigned*)(deg + Nd);
    unsigned* pairs2 = pairs1 + (size_t)nsb * SBCAP;
    size_t off_tmp = (((size_t)(8 * MAXSB + MAXB + Nd)
                      + (size_t)nsb * SBCAP + (size_t)nb * BCAP) * 4 + 255)
                     & ~(size_t)255;
    ushort* tmpb = (ushort*)((char*)d_ws + off_tmp);
    ushort* wpack = tmpb + (size_t)Nd * 128;
    ushort* w_bf16 = wpack + NPACK;
    unsigned* h  = (unsigned*)(w_bf16 + VD);

    size_t need_common = off_tmp + (size_t)Nd * 256 + (size_t)NPACK * 2;
    size_t need_A = need_common + (size_t)VD * 2;
    size_t need_B = need_A + (size_t)Ns * 64;
    int mode = (ws_size >= need_B) ? 2 : (ws_size >= need_A) ? 1 : 0;

    float* out = (float*)d_out;

    int nzc = (nb + 255) >> 8;
    int ncb = (mode >= 1) ? (VD / 4 + 255) / 256 : 0;
    hipLaunchKernelGGL(setup_all, dim3(nzc + 1 + ncb), dim3(256), 0, stream,
                       sbcursor, gcur, nb, nsb, W_agg, W1, W2, wpack,
                       w, w_bf16, VD, mode >= 1);
    if (mode == 2) {
        int hb = (Ns + 255) / 256;
        hipLaunchKernelGGL(build_h2, dim3(hb), dim3(256), 0, stream,
                           Cat_src, w_bf16, h, Ns);
    }
    hipLaunchKernelGGL(scatter_sb, dim3((E + TILE - 1) / TILE), dim3(256), 0, stream,
                       src_ids, dst_ids, sbcursor, pairs1, E, nsb);
    hipLaunchKernelGGL(scatter_fine, dim3(nsb * SEG), dim3(256), 0, stream,
                       pairs1, sbcursor, gcur, pairs2, nb, nsb);
    if (mode == 2) {
        hipLaunchKernelGGL(agg_from_h3, dim3(nb), dim3(256), 0, stream,
                           h, gcur, pairs2, tmpb, deg, Nd);
    } else {
        hipLaunchKernelGGL(agg_from_w, dim3(nb), dim3(256), 0, stream,
                           Cat_src, w, w_bf16, mode, gcur, pairs2,
                           tmpb, deg, Nd);
    }
    hipLaunchKernelGGL(finalize_mfma, dim3((Nd + 63) / 64), dim3(256), 0, stream,
                       Cat_dst, label, w, wpack, b_agg, w_lin, b_lin,
                       b1, b2, W3, b3, deg, tmpb, out, Nd);
}

// Round 13
// 286.061 us; speedup vs baseline: 1.0534x; 1.0075x over previous
//
#include <hip/hip_runtime.h>
#include <math.h>

#define EPSF 1e-5f
#define BSH  5         // log2(fine bucket size in dst nodes)
#define BSZ  32        // dst nodes per fine bucket
#define MAXB 4096      // max fine buckets (Nd/32); Nd=100k -> 3125
#define SBH  9         // log2(superbucket size) = 512 dst nodes
#define MAXSB 256      // max superbuckets; Nd=100k -> 196
#define TILE 2048      // edges per scatter_sb tile (1563 blocks, ~6/CU)
#define SEG  8         // segments per superbucket = cursor shards
#define BCAP 1472      // fine bucket capacity (avg 1024, +14 sigma)
#define SBCAP (16 * BCAP)  // superbucket capacity
#define SHCAP (SBCAP / 8)  // per-shard superbucket span (2944; fill~2054,+19s)
#define CAPW 88        // per-dst LDS row capacity (Poisson(32) + ~10 sigma)
#define XPADS2 104     // x row stride in ushorts (96 + 8)
#define X2PADS 72      // h1 row stride in shorts (64 + 8)
#define NPACK 14336    // packed bf16 weight elements (Wagg 6144 | W1 6144 | W2 2048)

typedef __attribute__((ext_vector_type(8))) short short8;
typedef __attribute__((ext_vector_type(4))) float float4v;
typedef __attribute__((ext_vector_type(4))) unsigned uint4v;

__device__ inline unsigned f2bf_rne(float x) {
    unsigned u = __float_as_uint(x);
    u += 0x7FFF + ((u >> 16) & 1);
    return u >> 16;
}
__device__ inline short bf16_of(float x) { return (short)f2bf_rne(x); }
__device__ inline float bf2f_lo(unsigned hv) { return __uint_as_float(hv << 16); }
__device__ inline float bf2f_hi(unsigned hv) { return __uint_as_float(hv & 0xFFFF0000u); }
__device__ inline float bf2f_s(ushort s) { return __uint_as_float((unsigned)s << 16); }

// ---- setup: strided cursor init | pack dense weights | cast w to bf16 -----
__global__ __launch_bounds__(256) void setup_all(
    int* sbcursor, int* gcur, int nb, int nsb,
    const float* __restrict__ W_agg, const float* __restrict__ W1,
    const float* __restrict__ W2, ushort* __restrict__ wpack,
    const float* __restrict__ w, ushort* __restrict__ wb, int VD, int do_cast)
{
    int nzc = (nb + 255) >> 8;
    int bid = blockIdx.x;
    if (bid < nzc) {
        int i = bid * 256 + threadIdx.x;
        if (i < nb) gcur[i] = i * BCAP;
        if (i < 8 * MAXSB) {                 // sharded cursors [shard][sb]
            int s = i >> 8;                  // MAXSB == 256
            int sb = i & (MAXSB - 1);
            sbcursor[i] = sb * SBCAP + s * SHCAP;
        }
        return;
    }
    if (bid == nzc) {
        for (int it = threadIdx.x; it < 1792; it += 256) {
            if (it < 768) {                       // W_agg [2][192][16]
                int t_g = it >> 6; int rem = it & 63;
                int q = rem >> 4, col = rem & 15;
                int kvar = t_g / 6, t = t_g % 6;
                const float* src = W_agg + kvar * 3072 + (t * 32 + q * 8) * 16 + col;
                ushort* dst = wpack + (size_t)it * 8;
#pragma unroll
                for (int j = 0; j < 8; ++j) dst[j] = (ushort)f2bf_rne(src[j * 16]);
            } else if (it < 1536) {               // W1 [96][64]
                int i2 = it - 768;
                int t = i2 >> 8; int rem = i2 & 255;
                int q = rem >> 6, col = rem & 63;
                const float* src = W1 + (t * 32 + q * 8) * 64 + col;
                ushort* dst = wpack + 6144 + (size_t)i2 * 8;
#pragma unroll
                for (int j = 0; j < 8; ++j) dst[j] = (ushort)f2bf_rne(src[j * 64]);
            } else {                              // W2 [64][32]
                int i2 = it - 1536;
                int t = i2 >> 7; int rem = i2 & 127;
                int q = rem >> 5, col = rem & 31;
                const float* src = W2 + (t * 32 + q * 8) * 32 + col;
                ushort* dst = wpack + 12288 + (size_t)i2 * 8;
#pragma unroll
                for (int j = 0; j < 8; ++j) dst[j] = (ushort)f2bf_rne(src[j * 32]);
            }
        }
        return;
    }
    if (!do_cast) return;
    int i4 = ((bid - nzc - 1) * 256 + threadIdx.x) * 4;
    if (i4 + 3 < VD) {
        float4 v = *(const float4*)(w + i4);
        ushort4 o;
        o.x = (ushort)f2bf_rne(v.x); o.y = (ushort)f2bf_rne(v.y);
        o.z = (ushort)f2bf_rne(v.z); o.w = (ushort)f2bf_rne(v.w);
        *(ushort4*)(wb + i4) = o;
    } else {
        for (int j = i4; j < VD; ++j) wb[j] = (ushort)f2bf_rne(w[j]);
    }
}

// ------ precompute h_src: one THREAD per source node, wide ld/st -----------
// h[s*16+d] = bf16(mean_f w[cat]) | bf16(max_f w[cat]) << 16
__global__ __launch_bounds__(256) void build_h2(
    const int* __restrict__ Cat_src, const ushort* __restrict__ wb,
    unsigned* __restrict__ h, int Ns)
{
    int s = blockIdx.x * 256 + threadIdx.x;
    if (s >= Ns) return;
    int4 c = *(const int4*)(Cat_src + (size_t)s * 4);
    const short8* r0 = (const short8*)(wb + (size_t)c.x * 16);
    const short8* r1 = (const short8*)(wb + (size_t)c.y * 16);
    const short8* r2 = (const short8*)(wb + (size_t)c.z * 16);
    const short8* r3 = (const short8*)(wb + (size_t)c.w * 16);
    short8 a0 = r0[0], b0 = r0[1];     // 8 independent 16B loads in flight
    short8 a1 = r1[0], b1 = r1[1];
    short8 a2 = r2[0], b2 = r2[1];
    short8 a3 = r3[0], b3 = r3[1];
    uint4v o0, o1, o2, o3;
#pragma unroll
    for (int d = 0; d < 8; ++d) {
        float v0 = bf2f_s((ushort)a0[d]), v1 = bf2f_s((ushort)a1[d]);
        float v2 = bf2f_s((ushort)a2[d]), v3 = bf2f_s((ushort)a3[d]);
        float mean = (v0 + v1 + v2 + v3) * 0.25f;
        float mx = fmaxf(fmaxf(v0, v1), fmaxf(v2, v3));
        unsigned pk = f2bf_rne(mean) | (f2bf_rne(mx) << 16);
        if (d < 4) o0[d] = pk; else o1[d - 4] = pk;
    }
#pragma unroll
    for (int d = 0; d < 8; ++d) {
        float v0 = bf2f_s((ushort)b0[d]), v1 = bf2f_s((ushort)b1[d]);
        float v2 = bf2f_s((ushort)b2[d]), v3 = bf2f_s((ushort)b3[d]);
        float mean = (v0 + v1 + v2 + v3) * 0.25f;
        float mx = fmaxf(fmaxf(v0, v1), fmaxf(v2, v3));
        unsigned pk = f2bf_rne(mean) | (f2bf_rne(mx) << 16);
        if (d < 4) o2[d] = pk; else o3[d - 4] = pk;
    }
    uint4v* hp = (uint4v*)(h + (size_t)s * 16);
    __builtin_nontemporal_store(o0, hp);
    __builtin_nontemporal_store(o1, hp + 1);
    __builtin_nontemporal_store(o2, hp + 2);
    __builtin_nontemporal_store(o3, hp + 3);
}

// ------- pass 1: scatter edges into sharded superbucket regions ------------
// pair = (src << 9) | (dst & 511); shard = blockIdx&7
__global__ __launch_bounds__(256) void scatter_sb(
    const int* __restrict__ src_ids, const int* __restrict__ dst_ids,
    int* sbcursor, unsigned* __restrict__ pairs1, int E, int nsb)
{
    __shared__ int cnt[MAXSB];
    __shared__ int base[MAXSB];
    int tid = threadIdx.x;
    int t0 = blockIdx.x * TILE;
    int shard = blockIdx.x & 7;
    for (int i = tid; i < nsb; i += 256) cnt[i] = 0;
    __syncthreads();
    int dj[2][4];
    int rank[2][4];
#pragma unroll
    for (int j = 0; j < 2; ++j) {
        int e4 = t0 + (j * 256 + tid) * 4;
        if (e4 + 3 < E) {
            int4 dd = *(const int4*)(dst_ids + e4);
            dj[j][0] = dd.x; dj[j][1] = dd.y; dj[j][2] = dd.z; dj[j][3] = dd.w;
#pragma unroll
            for (int k = 0; k < 4; ++k)
                rank[j][k] = atomicAdd(&cnt[dj[j][k] >> SBH], 1);
        } else {
#pragma unroll
            for (int k = 0; k < 4; ++k) {
                int e = e4 + k;
                dj[j][k] = (e < E) ? dst_ids[e] : 0;
                rank[j][k] = (e < E) ? atomicAdd(&cnt[dj[j][k] >> SBH], 1) : 0;
            }
        }
    }
    __syncthreads();
    for (int i = tid; i < nsb; i += 256) {
        int c = cnt[i];
        base[i] = c ? atomicAdd(&sbcursor[shard * MAXSB + i], c) : 0;
    }
    __syncthreads();
#pragma unroll
    for (int j = 0; j < 2; ++j) {
        int e4 = t0 + (j * 256 + tid) * 4;
        if (e4 + 3 < E) {
            int4 sv = *(const int4*)(src_ids + e4);
            int sj[4] = {sv.x, sv.y, sv.z, sv.w};
#pragma unroll
            for (int k = 0; k < 4; ++k) {
                int d = dj[j][k];
                int sb = d >> SBH;
                int idx = base[sb] + rank[j][k];
                if (idx < sb * SBCAP + (shard + 1) * SHCAP)   // shard guard
                    pairs1[idx] = ((unsigned)sj[k] << 9) | (unsigned)(d & 511);
            }
        } else {
#pragma unroll
            for (int k = 0; k < 4; ++k) {
                int e = e4 + k;
                if (e < E) {
                    int d = dj[j][k];
                    int sb = d >> SBH;
                    int idx = base[sb] + rank[j][k];
                    if (idx < sb * SBCAP + (shard + 1) * SHCAP)
                        pairs1[idx] = ((unsigned)src_ids[e] << 9)
                                    | (unsigned)(d & 511);
                }
            }
        }
    }
}

// ------- pass 2: scratch-free two-pass deal to fine buckets ----------------
// seg == shard; count per-wave -> claim base -> re-read & deal via per-wave
// cursors. No per-thread arrays (no scratch); per-wave counter rows cut
// LDS-atomic same-address contention 4x. Second read is L2-resident.
__global__ __launch_bounds__(256) void scatter_fine7(
    const unsigned* __restrict__ pairs1, const int* __restrict__ sbcursor,
    int* gcur, unsigned* __restrict__ pairs2, int nb, int nsb)
{
    __shared__ int cw[4][16];    // per-wave counts
    __shared__ int wofs[4][16];  // per-wave cursors
    int S = blockIdx.x >> 3, seg = blockIdx.x & (SEG - 1);
    int tid = threadIdx.x;
    int wv = tid >> 6;
    int s0 = S * SBCAP + seg * SHCAP;
    int s1 = sbcursor[seg * MAXSB + S];          // shard cursor after pass 1
    if (s1 > s0 + SHCAP) s1 = s0 + SHCAP;
    if (tid < 64) cw[tid >> 4][tid & 15] = 0;
    __syncthreads();
    for (int e = s0 + tid; e < s1; e += 256) {   // pass A: count
        unsigned p = pairs1[e];
        atomicAdd(&cw[wv][(p >> 5) & 15], 1);
    }
    __syncthreads();
    if (tid < 16) {
        int c0 = cw[0][tid], c1 = cw[1][tid], c2 = cw[2][tid], c3 = cw[3][tid];
        int tot = c0 + c1 + c2 + c3;
        int gb = (S << 4) + tid;
        int b = (tot && gb < nb) ? atomicAdd(&gcur[gb], tot) : 0;
        wofs[0][tid] = b;
        wofs[1][tid] = b + c0;
        wofs[2][tid] = b + c0 + c1;
        wofs[3][tid] = b + c0 + c1 + c2;
    }
    __syncthreads();
    for (int e = s0 + tid; e < s1; e += 256) {   // pass B: re-read & deal
        unsigned p = pairs1[e];
        int fb = (p >> 5) & 15;
        int gb = (S << 4) + fb;
        int idx = atomicAdd(&wofs[wv][fb], 1);
        if (idx < (gb + 1) * BCAP)               // capacity guard
            pairs2[idx] = p;
    }
}

// ====== shared helpers =====================================================

__device__ inline void bucket_sort(const unsigned* __restrict__ pairs,
                                   int gbase, int cnt,
                                   unsigned* sp, int* hist, int* ofs, int* start,
                                   int tid)
{
    if (tid < BSZ) hist[tid] = 0;
    __syncthreads();
    for (int i = tid; i < cnt; i += 256)
        atomicAdd(&hist[__builtin_nontemporal_load(&pairs[gbase + i]) & (BSZ - 1)], 1);
    __syncthreads();
    if (tid < BSZ) ofs[tid] = hist[tid];
    __syncthreads();
    for (int off = 1; off < BSZ; off <<= 1) {
        int y = (tid < BSZ && tid >= off) ? ofs[tid - off] : 0;
        __syncthreads();
        if (tid < BSZ) ofs[tid] += y;
        __syncthreads();
    }
    if (tid < BSZ) {
        start[tid] = ofs[tid] - hist[tid];
        ofs[tid] = ofs[tid] - hist[tid];
    }
    __syncthreads();
    for (int i = tid; i < cnt; i += 256) {
        unsigned p = __builtin_nontemporal_load(&pairs[gbase + i]);
        int r = atomicAdd(&ofs[p & (BSZ - 1)], 1);
        sp[r] = p;
    }
    __syncthreads();
}

__device__ inline void emit_stats(float sum0, float sq0, float mn0, float mx0,
                                  float sum1, float sq1, float mn1, float mx1,
                                  int dg, int n, int lane, int sub,
                                  ushort* __restrict__ tmpb, int* __restrict__ deg_out)
{
#pragma unroll
    for (int off = 16; off <= 32; off <<= 1) {
        sum0 += __shfl_xor(sum0, off); sq0 += __shfl_xor(sq0, off);
        mn0 = fminf(mn0, __shfl_xor(mn0, off)); mx0 = fmaxf(mx0, __shfl_xor(mx0, off));
        sum1 += __shfl_xor(sum1, off); sq1 += __shfl_xor(sq1, off);
        mn1 = fminf(mn1, __shfl_xor(mn1, off)); mx1 = fmaxf(mx1, __shfl_xor(mx1, off));
    }
    float safe = fmaxf((float)dg, 1.f);
    float r = 1.f / safe;
    bool has = dg > 0;
    float mean0 = sum0 * r, mean1 = sum1 * r;
    float sd0 = sqrtf(fmaxf(sq0 * r - mean0 * mean0, 0.f) + EPSF);
    float sd1 = sqrtf(fmaxf(sq1 * r - mean1 * mean1, 0.f) + EPSF);
    float v0 = (sub == 0) ? mean0 : (sub == 1) ? (has ? mn0 : 0.f)
             : (sub == 2) ? (has ? mx0 : 0.f) : sd0;
    float v1 = (sub == 0) ? mean1 : (sub == 1) ? (has ? mn1 : 0.f)
             : (sub == 2) ? (has ? mx1 : 0.f) : sd1;
    ushort* tp = tmpb + (size_t)n * 128;
    tp[lane] = (ushort)f2bf_rne(v0);
    tp[64 + lane] = (ushort)f2bf_rne(v1);
    if (lane == 0) deg_out[n] = dg;
}

// ---- gather from packed h; 512 threads = 8 waves/block for occupancy ------
// 4 blocks x 11.4KB LDS = 45.6KB < 64KB pool; 4 x 8 = 32 waves/CU (100%).
// Single-pass LDS deal (1 atomic + 1 store per edge); 4 nodes per wave.
__global__ __launch_bounds__(512) void agg_from_h3(
    const unsigned* __restrict__ h, const int* __restrict__ gcur,
    const unsigned* __restrict__ pairs,
    ushort* __restrict__ tmpb, int* __restrict__ deg_out, int Nd)
{
    __shared__ unsigned sp[BSZ * CAPW];    // 11264 B
    __shared__ int cnt[BSZ];
    int b = blockIdx.x, tid = threadIdx.x;
    int gbase = b * BCAP;
    int ecnt = gcur[b] - gbase;
    if (ecnt > BCAP) ecnt = BCAP;
    if (ecnt < 0) ecnt = 0;
    if (tid < BSZ) cnt[tid] = 0;
    __syncthreads();
    for (int i = tid; i < ecnt; i += 512) {
        unsigned p = __builtin_nontemporal_load(&pairs[gbase + i]);
        int dl = (int)(p & (BSZ - 1));
        int r = atomicAdd(&cnt[dl], 1);
        if (r < CAPW) sp[dl * CAPW + r] = p;   // per-dst cap: ~10 sigma guard
    }
    __syncthreads();

    int wv = tid >> 6, lane = tid & 63, sub = lane >> 4, d = lane & 15;
#pragma unroll 1
    for (int q = 0; q < 4; ++q) {
        int dl = wv * 4 + q;
        int n = b * BSZ + dl;
        if (n >= Nd) break;
        int dg = cnt[dl];
        int dgc = (dg < CAPW) ? dg : CAPW;
        const unsigned* swp = sp + dl * CAPW;
        float sum0 = 0.f, sq0 = 0.f, mn0 = INFINITY, mx0 = -INFINITY;
        float sum1 = 0.f, sq1 = 0.f, mn1 = INFINITY, mx1 = -INFINITY;
        int nt = (dgc + 31) >> 5;          // 32 edges per wave-iteration
        for (int t = 0; t < nt; ++t) {
            int base = t * 32 + sub;
            unsigned hv[8];
#pragma unroll
            for (int j = 0; j < 8; ++j) {   // 8 independent gathers in flight
                int e = base + j * 4;
                int ec = (e < dgc) ? e : (dgc - 1);
                unsigned p = swp[ec];
                hv[j] = h[(p >> 9) * 16 + d];
            }
#pragma unroll
            for (int j = 0; j < 8; ++j) {
                int e = base + j * 4;
                if (e < dgc) {
                    float me = bf2f_lo(hv[j]);
                    float vm = bf2f_hi(hv[j]);
                    sum0 += me; sq0 += me * me;
                    mn0 = fminf(mn0, me); mx0 = fmaxf(mx0, me);
                    sum1 += vm; sq1 += vm * vm;
                    mn1 = fminf(mn1, vm); mx1 = fmaxf(mx1, vm);
                }
            }
        }
        emit_stats(sum0, sq0, mn0, mx0, sum1, sq1, mn1, mx1,
                   dg, n, lane, sub, tmpb, deg_out);
    }
}

// ---- fallback: gather w per edge (bf16 table if use_bf, else fp32) --------
__global__ __launch_bounds__(256) void agg_from_w(
    const int* __restrict__ Cat_src, const float* __restrict__ w,
    const ushort* __restrict__ wb, int use_bf, const int* __restrict__ gcur,
    const unsigned* __restrict__ pairs,
    ushort* __restrict__ tmpb, int* __restrict__ deg_out, int Nd)
{
    __shared__ unsigned sp[BCAP];
    __shared__ int hist[BSZ];
    __shared__ int ofs[BSZ];
    __shared__ int start[BSZ];
    int b = blockIdx.x, tid = threadIdx.x;
    int gbase = b * BCAP;
    int cnt = gcur[b] - gbase;
    if (cnt > BCAP) cnt = BCAP;
    if (cnt < 0) cnt = 0;
    bucket_sort(pairs, gbase, cnt, sp, hist, ofs, start, tid);

    int wv = tid >> 6, lane = tid & 63, sub = lane >> 4, d = lane & 15;
#pragma unroll 1
    for (int q = 0; q < 8; ++q) {
        int dl = wv * 8 + q;
        int n = b * BSZ + dl;
        if (n >= Nd) break;
        int st = start[dl], dg = hist[dl];
        float sum0 = 0.f, sq0 = 0.f, mn0 = INFINITY, mx0 = -INFINITY;
        float sum1 = 0.f, sq1 = 0.f, mn1 = INFINITY, mx1 = -INFINITY;
        int nt = (dg + 3) >> 2;
        for (int t = 0; t < nt; ++t) {
            int e4 = t * 4 + sub;
            int ec = (e4 < dg) ? e4 : (dg - 1);
            unsigned p = sp[st + ec];
            int src = (int)(p >> 9);
            int cat = Cat_src[src * 4 + (d & 3)];
            float vs = 0.f, vm = -INFINITY;
            if (use_bf) {
#pragma unroll
                for (int f = 0; f < 4; ++f) {
                    int id = __shfl(cat, sub * 16 + f, 64);
                    float a = bf2f_s(wb[id * 16 + d]);
                    vs += a; vm = fmaxf(vm, a);
                }
            } else {
#pragma unroll
                for (int f = 0; f < 4; ++f) {
                    int id = __shfl(cat, sub * 16 + f, 64);
                    float a = w[id * 16 + d];
                    vs += a; vm = fmaxf(vm, a);
                }
            }
            if (e4 < dg) {
                float me = vs * 0.25f;
                sum0 += me; sq0 += me * me;
                mn0 = fminf(mn0, me); mx0 = fmaxf(mx0, me);
                sum1 += vm; sq1 += vm * vm;
                mn1 = fminf(mn1, vm); mx1 = fmaxf(mx1, vm);
            }
        }
        emit_stats(sum0, sq0, mn0, mx0, sum1, sq1, mn1, mx1,
                   dg, n, lane, sub, tmpb, deg_out);
    }
}

// ---------------- finalize via MFMA, packed weights, bf16 X buffer ---------
// Layouts (gfx950, verified): A[m=lane&15][k=(lane>>4)*8+j];
// B[k][n=lane&15]; C/D col=lane&15, row=(lane>>4)*4+reg.
__global__ __launch_bounds__(256) void finalize_mfma(
    const int* __restrict__ Cat_dst, const int* __restrict__ label,
    const float* __restrict__ w, const ushort* __restrict__ wpack,
    const float* __restrict__ b_agg,
    const float* __restrict__ w_lin, const float* __restrict__ b_lin,
    const float* __restrict__ b1, const float* __restrict__ b2,
    const float* __restrict__ W3, const float* __restrict__ b3,
    const int* __restrict__ deg_arr, const ushort* __restrict__ tmpb,
    float* __restrict__ out, int Nd)
{
    __shared__ __align__(16) ushort sx[4][16 * XPADS2];  // x, bf16
    __shared__ __align__(16) ushort sx2[4][16 * X2PADS]; // h1, bf16
    __shared__ float sdeep[4][16];

    int tid = threadIdx.x;
    int wv = tid >> 6, lane = tid & 63;
    int q = lane >> 4, m = lane & 15;
    int n0 = (blockIdx.x * 4 + wv) * 16;
    int n = n0 + m;
    int nc = (n < Nd) ? n : (Nd - 1);

    ushort* X = sx[wv];
    ushort* X2 = sx2[wv];

    float fdeg = (float)deg_arr[nc];
    float logd = logf(fdeg + 1.f);
    const float logavg = logf(33.0f);
    float amp = logd / logavg;
    float att = (logd > 0.f) ? (logavg / fmaxf(logd, EPSF)) : 0.f;
    float ampr[4], attr[4];
#pragma unroll
    for (int r = 0; r < 4; ++r) {
        ampr[r] = __shfl(amp, q * 4 + r, 64);
        attr[r] = __shfl(att, q * 4 + r, 64);
    }

    // Phase A: mes = scaled @ W_agg + b_agg, scalers folded post-MFMA
    const ushort* tpn = tmpb + (size_t)nc * 128;
#pragma unroll
    for (int kvar = 0; kvar < 2; ++kvar) {
        short8 af0 = *(const short8*)(tpn + kvar * 64 + q * 8);
        short8 af1 = *(const short8*)(tpn + kvar * 64 + 32 + q * 8);
        float4v aI = {0.f,0.f,0.f,0.f}, aA = {0.f,0.f,0.f,0.f}, aT = {0.f,0.f,0.f,0.f};
#pragma unroll
        for (int sb = 0; sb < 3; ++sb) {
            short8 b0 = *(const short8*)(wpack +
                (size_t)(((kvar * 6 + sb * 2) * 4 + q) * 16 + m) * 8);
            short8 b1v = *(const short8*)(wpack +
                (size_t)(((kvar * 6 + sb * 2 + 1) * 4 + q) * 16 + m) * 8);
            if (sb == 0) {
                aI = __builtin_amdgcn_mfma_f32_16x16x32_bf16(af0, b0, aI, 0, 0, 0);
                aI = __builtin_amdgcn_mfma_f32_16x16x32_bf16(af1, b1v, aI, 0, 0, 0);
            } else if (sb == 1) {
                aA = __builtin_amdgcn_mfma_f32_16x16x32_bf16(af0, b0, aA, 0, 0, 0);
                aA = __builtin_amdgcn_mfma_f32_16x16x32_bf16(af1, b1v, aA, 0, 0, 0);
            } else {
                aT = __builtin_amdgcn_mfma_f32_16x16x32_bf16(af0, b0, aT, 0, 0, 0);
                aT = __builtin_amdgcn_mfma_f32_16x16x32_bf16(af1, b1v, aT, 0, 0, 0);
            }
        }
        float bias = b_agg[kvar * 16 + m];
#pragma unroll
        for (int r = 0; r < 4; ++r)
            X[(q * 4 + r) * XPADS2 + 64 + kvar * 16 + m] = (ushort)f2bf_rne(
                aI[r] + ampr[r] * aA[r] + attr[r] * aT[r] + bias);
    }
    // Phase B: dst cat embeddings -> X cols 0..63 (bf16)
    {
        int nl = lane >> 2, fl = lane & 3;
        int nn = n0 + nl;
        int nnc = (nn < Nd) ? nn : (Nd - 1);
        int cid = Cat_dst[nnc * 4 + fl];
        const float4* R = (const float4*)(w + (size_t)cid * 16);
        float4 r0 = R[0], r1 = R[1], r2 = R[2], r3 = R[3];
        short8 o0, o1;
        o0[0] = bf16_of(r0.x); o0[1] = bf16_of(r0.y);
        o0[2] = bf16_of(r0.z); o0[3] = bf16_of(r0.w);
        o0[4] = bf16_of(r1.x); o0[5] = bf16_of(r1.y);
        o0[6] = bf16_of(r1.z); o0[7] = bf16_of(r1.w);
        o1[0] = bf16_of(r2.x); o1[1] = bf16_of(r2.y);
        o1[2] = bf16_of(r2.z); o1[3] = bf16_of(r2.w);
        o1[4] = bf16_of(r3.x); o1[5] = bf16_of(r3.y);
        o1[6] = bf16_of(r3.z); o1[7] = bf16_of(r3.w);
        ushort* xp = X + nl * XPADS2 + fl * 16;
        *(short8*)(xp) = o0;
        *(short8*)(xp + 8) = o1;
    }
    __syncthreads();

    // Phase D: lin / FM stats for node m (q splits the 6 fields)
    float lin = 0.f, sq = 0.f;
    float sd[16];
#pragma unroll
    for (int u = 0; u < 16; ++u) sd[u] = 0.f;
    {
        const ushort* xp = X + m * XPADS2 + q * 16;
        const float* wl = w_lin + q * 16;
#pragma unroll
        for (int u = 0; u < 16; ++u) {
            float v = bf2f_s(xp[u]);
            lin += v * wl[u]; sq += v * v; sd[u] += v;
        }
    }
    if (q < 2) {
        const ushort* xp = X + m * XPADS2 + (4 + q) * 16;
        const float* wl = w_lin + (4 + q) * 16;
#pragma unroll
        for (int u = 0; u < 16; ++u) {
            float v = bf2f_s(xp[u]);
            lin += v * wl[u]; sq += v * v; sd[u] += v;
        }
    }
#pragma unroll
    for (int off = 16; off <= 32; off <<= 1) {
        lin += __shfl_xor(lin, off);
        sq  += __shfl_xor(sq, off);
#pragma unroll
        for (int u = 0; u < 16; ++u) sd[u] += __shfl_xor(sd[u], off);
    }
    float fm = 0.f;
#pragma unroll
    for (int u = 0; u < 16; ++u) fm += sd[u] * sd[u];
    fm = 0.5f * (fm - sq);

    // Phase E: h1 = relu(x @ W1 + b1), A-frags direct from bf16 X
    short8 xa[3];
#pragma unroll
    for (int t = 0; t < 3; ++t)
        xa[t] = *(const short8*)(X + m * XPADS2 + t * 32 + q * 8);
#pragma unroll
    for (int nt = 0; nt < 4; ++nt) {
        float4v acc = {0.f, 0.f, 0.f, 0.f};
#pragma unroll
        for (int t = 0; t < 3; ++t) {
            short8 bf = *(const short8*)(wpack + 6144 +
                (size_t)((t * 4 + q) * 64 + nt * 16 + m) * 8);
            acc = __builtin_amdgcn_mfma_f32_16x16x32_bf16(xa[t], bf, acc, 0, 0, 0);
        }
        float bb = b1[nt * 16 + m];
#pragma unroll
        for (int r = 0; r < 4; ++r)
            X2[(q * 4 + r) * X2PADS + nt * 16 + m] =
                (ushort)f2bf_rne(fmaxf(acc[r] + bb, 0.f));
    }
    __syncthreads();

    // Phase F: h2 = relu(h1 @ W2 + b2); deep = h2 @ W3
    short8 ha[2];
#pragma unroll
    for (int t = 0; t < 2; ++t)
        ha[t] = *(const short8*)(X2 + m * X2PADS + t * 32 + q * 8);
    float dp[4] = {0.f, 0.f, 0.f, 0.f};
#pragma unroll
    for (int nt = 0; nt < 2; ++nt) {
        float4v acc = {0.f, 0.f, 0.f, 0.f};
#pragma unroll
        for (int t = 0; t < 2; ++t) {
            short8 bf = *(const short8*)(wpack + 12288 +
                (size_t)((t * 4 + q) * 32 + nt * 16 + m) * 8);
            acc = __builtin_amdgcn_mfma_f32_16x16x32_bf16(ha[t], bf, acc, 0, 0, 0);
        }
        float bb = b2[nt * 16 + m];
        float w3 = W3[nt * 16 + m];
#pragma unroll
        for (int r = 0; r < 4; ++r)
            dp[r] += fmaxf(acc[r] + bb, 0.f) * w3;
    }
#pragma unroll
    for (int off = 1; off <= 8; off <<= 1) {
#pragma unroll
        for (int r = 0; r < 4; ++r) dp[r] += __shfl_xor(dp[r], off);
    }
    if (m < 4)
        sdeep[wv][q * 4 + m] = (m == 0) ? dp[0] : (m == 1) ? dp[1]
                             : (m == 2) ? dp[2] : dp[3];
    __syncthreads();
    float deep = sdeep[wv][m];

    if (q == 0 && n < Nd) {
        float z = lin + b_lin[0] + fm + deep + b3[0];
        float pred = 1.f / (1.f + expf(-z));
        out[n] = pred;
        out[Nd + n] = (float)label[n];
    }
}

extern "C" void kernel_launch(void* const* d_in, const int* in_sizes, int n_in,
                              void* d_out, int out_size, void* d_ws, size_t ws_size,
                              hipStream_t stream) {
    const int*   Cat_src = (const int*)d_in[0];
    const int*   Cat_dst = (const int*)d_in[1];
    const int*   src_ids = (const int*)d_in[2];
    const int*   dst_ids = (const int*)d_in[3];
    const int*   label   = (const int*)d_in[4];
    const float* w       = (const float*)d_in[5];
    const float* W_agg   = (const float*)d_in[6];
    const float* b_agg   = (const float*)d_in[7];
    const float* w_lin   = (const float*)d_in[8];
    const float* b_lin   = (const float*)d_in[9];
    const float* W1      = (const float*)d_in[10];
    const float* b1      = (const float*)d_in[11];
    const float* W2      = (const float*)d_in[12];
    const float* b2      = (const float*)d_in[13];
    const float* W3      = (const float*)d_in[14];
    const float* b3      = (const float*)d_in[15];

    int E  = in_sizes[2];
    int Nd = in_sizes[4];
    int Ns = in_sizes[0] / 4;
    int VD = in_sizes[5];
    int nb  = (Nd + BSZ - 1) >> BSH;
    int nsb = (nb + 15) >> 4;

    // ws layout: sbcursor[8*MAXSB] | gcur[MAXB] | deg[Nd]
    //            | pairs1[nsb*SBCAP] | pairs2[nb*BCAP] | (align)
    //            | tmpb[Nd*128 us] | wpack[NPACK us] | w_bf16[VD us] | h[Ns*16]
    int* sbcursor = (int*)d_ws;
    int* gcur     = sbcursor + 8 * MAXSB;
    int* deg      = gcur + MAXB;
    unsigned* pairs1 = (unsigned*)(deg + Nd);
    unsigned* pairs2 = pairs1 + (size_t)nsb * SBCAP;
    size_t off_tmp = (((size_t)(8 * MAXSB + MAXB + Nd)
                      + (size_t)nsb * SBCAP + (size_t)nb * BCAP) * 4 + 255)
                     & ~(size_t)255;
    ushort* tmpb = (ushort*)((char*)d_ws + off_tmp);
    ushort* wpack = tmpb + (size_t)Nd * 128;
    ushort* w_bf16 = wpack + NPACK;
    unsigned* h  = (unsigned*)(w_bf16 + VD);

    size_t need_common = off_tmp + (size_t)Nd * 256 + (size_t)NPACK * 2;
    size_t need_A = need_common + (size_t)VD * 2;
    size_t need_B = need_A + (size_t)Ns * 64;
    int mode = (ws_size >= need_B) ? 2 : (ws_size >= need_A) ? 1 : 0;

    float* out = (float*)d_out;

    int nzc = (nb + 255) >> 8;
    int ncb = (mode >= 1) ? (VD / 4 + 255) / 256 : 0;
    hipLaunchKernelGGL(setup_all, dim3(nzc + 1 + ncb), dim3(256), 0, stream,
                       sbcursor, gcur, nb, nsb, W_agg, W1, W2, wpack,
                       w, w_bf16, VD, mode >= 1);
    if (mode == 2) {
        int hb = (Ns + 255) / 256;
        hipLaunchKernelGGL(build_h2, dim3(hb), dim3(256), 0, stream,
                           Cat_src, w_bf16, h, Ns);
    }
    hipLaunchKernelGGL(scatter_sb, dim3((E + TILE - 1) / TILE), dim3(256), 0, stream,
                       src_ids, dst_ids, sbcursor, pairs1, E, nsb);
    hipLaunchKernelGGL(scatter_fine7, dim3(nsb * SEG), dim3(256), 0, stream,
                       pairs1, sbcursor, gcur, pairs2, nb, nsb);
    if (mode == 2) {
        hipLaunchKernelGGL(agg_from_h3, dim3(nb), dim3(512), 0, stream,
                           h, gcur, pairs2, tmpb, deg, Nd);
    } else {
        hipLaunchKernelGGL(agg_from_w, dim3(nb), dim3(256), 0, stream,
                           Cat_src, w, w_bf16, mode, gcur, pairs2,
                           tmpb, deg, Nd);
    }
    hipLaunchKernelGGL(finalize_mfma, dim3((Nd + 63) / 64), dim3(256), 0, stream,
                       Cat_dst, label, w, wpack, b_agg, w_lin, b_lin,
                       b1, b2, W3, b3, deg, tmpb, out, Nd);
}

// Round 14
// 281.153 us; speedup vs baseline: 1.0717x; 1.0175x over previous
//
#include <hip/hip_runtime.h>
#include <math.h>

#define EPSF 1e-5f
#define BSH  5         // log2(fine bucket size in dst nodes)
#define BSZ  32        // dst nodes per fine bucket
#define MAXB 4096      // max fine buckets (Nd/32); Nd=100k -> 3125
#define SBH  9         // log2(superbucket size) = 512 dst nodes
#define MAXSB 256      // max superbuckets; Nd=100k -> 196
#define TILE 2048      // edges per scatter tile (1563 blocks, ~6/CU)
#define SEG  8         // segments per superbucket = cursor shards
#define BCAP 1472      // fine bucket capacity (avg 1024, +14 sigma)
#define SBCAP (16 * BCAP)  // superbucket capacity
#define SHCAP (SBCAP / 8)  // per-shard superbucket span (2944; fill~2054,+19s)
#define CAPW 88        // per-dst LDS row capacity (Poisson(32) + ~10 sigma)
#define XPADS2 104     // x row stride in ushorts (96 + 8)
#define X2PADS 72      // h1 row stride in shorts (64 + 8)
#define NPACK 14336    // packed bf16 weight elements (Wagg 6144 | W1 6144 | W2 2048)

typedef __attribute__((ext_vector_type(8))) short short8;
typedef __attribute__((ext_vector_type(4))) float float4v;
typedef __attribute__((ext_vector_type(4))) unsigned uint4v;

__device__ inline unsigned f2bf_rne(float x) {
    unsigned u = __float_as_uint(x);
    u += 0x7FFF + ((u >> 16) & 1);
    return u >> 16;
}
__device__ inline short bf16_of(float x) { return (short)f2bf_rne(x); }
__device__ inline float bf2f_lo(unsigned hv) { return __uint_as_float(hv << 16); }
__device__ inline float bf2f_hi(unsigned hv) { return __uint_as_float(hv & 0xFFFF0000u); }
__device__ inline float bf2f_s(ushort s) { return __uint_as_float((unsigned)s << 16); }

// ---- setup: strided cursor init | pack dense weights | cast w to bf16 -----
__global__ __launch_bounds__(256) void setup_all(
    int* sbcursor, int* gcur, int nb, int nsb,
    const float* __restrict__ W_agg, const float* __restrict__ W1,
    const float* __restrict__ W2, ushort* __restrict__ wpack,
    const float* __restrict__ w, ushort* __restrict__ wb, int VD, int do_cast)
{
    int nzc = (nb + 255) >> 8;
    int bid = blockIdx.x;
    if (bid < nzc) {
        int i = bid * 256 + threadIdx.x;
        if (i < nb) gcur[i] = i * BCAP;
        if (i < 8 * MAXSB) {                 // sharded cursors [shard][sb]
            int s = i >> 8;                  // MAXSB == 256
            int sb = i & (MAXSB - 1);
            sbcursor[i] = sb * SBCAP + s * SHCAP;
        }
        return;
    }
    if (bid == nzc) {
        for (int it = threadIdx.x; it < 1792; it += 256) {
            if (it < 768) {                       // W_agg [2][192][16]
                int t_g = it >> 6; int rem = it & 63;
                int q = rem >> 4, col = rem & 15;
                int kvar = t_g / 6, t = t_g % 6;
                const float* src = W_agg + kvar * 3072 + (t * 32 + q * 8) * 16 + col;
                ushort* dst = wpack + (size_t)it * 8;
#pragma unroll
                for (int j = 0; j < 8; ++j) dst[j] = (ushort)f2bf_rne(src[j * 16]);
            } else if (it < 1536) {               // W1 [96][64]
                int i2 = it - 768;
                int t = i2 >> 8; int rem = i2 & 255;
                int q = rem >> 6, col = rem & 63;
                const float* src = W1 + (t * 32 + q * 8) * 64 + col;
                ushort* dst = wpack + 6144 + (size_t)i2 * 8;
#pragma unroll
                for (int j = 0; j < 8; ++j) dst[j] = (ushort)f2bf_rne(src[j * 64]);
            } else {                              // W2 [64][32]
                int i2 = it - 1536;
                int t = i2 >> 7; int rem = i2 & 127;
                int q = rem >> 5, col = rem & 31;
                const float* src = W2 + (t * 32 + q * 8) * 32 + col;
                ushort* dst = wpack + 12288 + (size_t)i2 * 8;
#pragma unroll
                for (int j = 0; j < 8; ++j) dst[j] = (ushort)f2bf_rne(src[j * 32]);
            }
        }
        return;
    }
    if (!do_cast) return;
    int i4 = ((bid - nzc - 1) * 256 + threadIdx.x) * 4;
    if (i4 + 3 < VD) {
        float4 v = *(const float4*)(w + i4);
        ushort4 o;
        o.x = (ushort)f2bf_rne(v.x); o.y = (ushort)f2bf_rne(v.y);
        o.z = (ushort)f2bf_rne(v.z); o.w = (ushort)f2bf_rne(v.w);
        *(ushort4*)(wb + i4) = o;
    } else {
        for (int j = i4; j < VD; ++j) wb[j] = (ushort)f2bf_rne(w[j]);
    }
}

// ==== fused: scatter_sb (blocks < nscb) + build_h2 (rest) ==================
// independent passes sharing one dispatch: scatter is latency-bound (stalls),
// build is BW-bound -> co-resident waves interleave; saves 1 drain boundary.
__global__ __launch_bounds__(256) void sb_and_build(
    const int* __restrict__ src_ids, const int* __restrict__ dst_ids,
    int* sbcursor, unsigned* __restrict__ pairs1, int E, int nsb, int nscb,
    const int* __restrict__ Cat_src, const ushort* __restrict__ wb,
    unsigned* __restrict__ h, int Ns)
{
    __shared__ int cnt[MAXSB];
    __shared__ int base[MAXSB];
    int tid = threadIdx.x;
    if ((int)blockIdx.x >= nscb) {
        // ---- build_h2: one thread per source node, wide ld/st ----
        int s = ((int)blockIdx.x - nscb) * 256 + tid;
        if (s >= Ns) return;
        int4 c = *(const int4*)(Cat_src + (size_t)s * 4);
        const short8* r0 = (const short8*)(wb + (size_t)c.x * 16);
        const short8* r1 = (const short8*)(wb + (size_t)c.y * 16);
        const short8* r2 = (const short8*)(wb + (size_t)c.z * 16);
        const short8* r3 = (const short8*)(wb + (size_t)c.w * 16);
        short8 a0 = r0[0], b0 = r0[1];   // 8 independent 16B loads in flight
        short8 a1 = r1[0], b1 = r1[1];
        short8 a2 = r2[0], b2 = r2[1];
        short8 a3 = r3[0], b3 = r3[1];
        uint4v o0, o1, o2, o3;
#pragma unroll
        for (int d = 0; d < 8; ++d) {
            float v0 = bf2f_s((ushort)a0[d]), v1 = bf2f_s((ushort)a1[d]);
            float v2 = bf2f_s((ushort)a2[d]), v3 = bf2f_s((ushort)a3[d]);
            float mean = (v0 + v1 + v2 + v3) * 0.25f;
            float mx = fmaxf(fmaxf(v0, v1), fmaxf(v2, v3));
            unsigned pk = f2bf_rne(mean) | (f2bf_rne(mx) << 16);
            if (d < 4) o0[d] = pk; else o1[d - 4] = pk;
        }
#pragma unroll
        for (int d = 0; d < 8; ++d) {
            float v0 = bf2f_s((ushort)b0[d]), v1 = bf2f_s((ushort)b1[d]);
            float v2 = bf2f_s((ushort)b2[d]), v3 = bf2f_s((ushort)b3[d]);
            float mean = (v0 + v1 + v2 + v3) * 0.25f;
            float mx = fmaxf(fmaxf(v0, v1), fmaxf(v2, v3));
            unsigned pk = f2bf_rne(mean) | (f2bf_rne(mx) << 16);
            if (d < 4) o2[d] = pk; else o3[d - 4] = pk;
        }
        uint4v* hp = (uint4v*)(h + (size_t)s * 16);
        __builtin_nontemporal_store(o0, hp);
        __builtin_nontemporal_store(o1, hp + 1);
        __builtin_nontemporal_store(o2, hp + 2);
        __builtin_nontemporal_store(o3, hp + 3);
        return;
    }
    // ---- scatter_sb: pair = (src << 9) | (dst & 511); shard = bid&7 ----
    int t0 = blockIdx.x * TILE;
    int shard = blockIdx.x & 7;
    for (int i = tid; i < nsb; i += 256) cnt[i] = 0;
    __syncthreads();
    int dj[2][4];
    int rank[2][4];
#pragma unroll
    for (int j = 0; j < 2; ++j) {
        int e4 = t0 + (j * 256 + tid) * 4;
        if (e4 + 3 < E) {
            int4 dd = *(const int4*)(dst_ids + e4);
            dj[j][0] = dd.x; dj[j][1] = dd.y; dj[j][2] = dd.z; dj[j][3] = dd.w;
#pragma unroll
            for (int k = 0; k < 4; ++k)
                rank[j][k] = atomicAdd(&cnt[dj[j][k] >> SBH], 1);
        } else {
#pragma unroll
            for (int k = 0; k < 4; ++k) {
                int e = e4 + k;
                dj[j][k] = (e < E) ? dst_ids[e] : 0;
                rank[j][k] = (e < E) ? atomicAdd(&cnt[dj[j][k] >> SBH], 1) : 0;
            }
        }
    }
    __syncthreads();
    for (int i = tid; i < nsb; i += 256) {
        int c = cnt[i];
        base[i] = c ? atomicAdd(&sbcursor[shard * MAXSB + i], c) : 0;
    }
    __syncthreads();
#pragma unroll
    for (int j = 0; j < 2; ++j) {
        int e4 = t0 + (j * 256 + tid) * 4;
        if (e4 + 3 < E) {
            int4 sv = *(const int4*)(src_ids + e4);
            int sj[4] = {sv.x, sv.y, sv.z, sv.w};
#pragma unroll
            for (int k = 0; k < 4; ++k) {
                int d = dj[j][k];
                int sb = d >> SBH;
                int idx = base[sb] + rank[j][k];
                if (idx < sb * SBCAP + (shard + 1) * SHCAP)   // shard guard
                    pairs1[idx] = ((unsigned)sj[k] << 9) | (unsigned)(d & 511);
            }
        } else {
#pragma unroll
            for (int k = 0; k < 4; ++k) {
                int e = e4 + k;
                if (e < E) {
                    int d = dj[j][k];
                    int sb = d >> SBH;
                    int idx = base[sb] + rank[j][k];
                    if (idx < sb * SBCAP + (shard + 1) * SHCAP)
                        pairs1[idx] = ((unsigned)src_ids[e] << 9)
                                    | (unsigned)(d & 511);
                }
            }
        }
    }
}

// ------- pass 2: scratch-free two-pass deal to fine buckets ----------------
__global__ __launch_bounds__(256) void scatter_fine7(
    const unsigned* __restrict__ pairs1, const int* __restrict__ sbcursor,
    int* gcur, unsigned* __restrict__ pairs2, int nb, int nsb)
{
    __shared__ int cw[4][16];    // per-wave counts
    __shared__ int wofs[4][16];  // per-wave cursors
    int S = blockIdx.x >> 3, seg = blockIdx.x & (SEG - 1);
    int tid = threadIdx.x;
    int wv = tid >> 6;
    int s0 = S * SBCAP + seg * SHCAP;
    int s1 = sbcursor[seg * MAXSB + S];          // shard cursor after pass 1
    if (s1 > s0 + SHCAP) s1 = s0 + SHCAP;
    if (tid < 64) cw[tid >> 4][tid & 15] = 0;
    __syncthreads();
    for (int e = s0 + tid; e < s1; e += 256) {   // pass A: count
        unsigned p = pairs1[e];
        atomicAdd(&cw[wv][(p >> 5) & 15], 1);
    }
    __syncthreads();
    if (tid < 16) {
        int c0 = cw[0][tid], c1 = cw[1][tid], c2 = cw[2][tid], c3 = cw[3][tid];
        int tot = c0 + c1 + c2 + c3;
        int gb = (S << 4) + tid;
        int b = (tot && gb < nb) ? atomicAdd(&gcur[gb], tot) : 0;
        wofs[0][tid] = b;
        wofs[1][tid] = b + c0;
        wofs[2][tid] = b + c0 + c1;
        wofs[3][tid] = b + c0 + c1 + c2;
    }
    __syncthreads();
    for (int e = s0 + tid; e < s1; e += 256) {   // pass B: re-read & deal
        unsigned p = pairs1[e];
        int fb = (p >> 5) & 15;
        int gb = (S << 4) + fb;
        int idx = atomicAdd(&wofs[wv][fb], 1);
        if (idx < (gb + 1) * BCAP)               // capacity guard
            pairs2[idx] = p;
    }
}

// ====== shared helpers =====================================================

__device__ inline void bucket_sort(const unsigned* __restrict__ pairs,
                                   int gbase, int cnt,
                                   unsigned* sp, int* hist, int* ofs, int* start,
                                   int tid)
{
    if (tid < BSZ) hist[tid] = 0;
    __syncthreads();
    for (int i = tid; i < cnt; i += 256)
        atomicAdd(&hist[__builtin_nontemporal_load(&pairs[gbase + i]) & (BSZ - 1)], 1);
    __syncthreads();
    if (tid < BSZ) ofs[tid] = hist[tid];
    __syncthreads();
    for (int off = 1; off < BSZ; off <<= 1) {
        int y = (tid < BSZ && tid >= off) ? ofs[tid - off] : 0;
        __syncthreads();
        if (tid < BSZ) ofs[tid] += y;
        __syncthreads();
    }
    if (tid < BSZ) {
        start[tid] = ofs[tid] - hist[tid];
        ofs[tid] = ofs[tid] - hist[tid];
    }
    __syncthreads();
    for (int i = tid; i < cnt; i += 256) {
        unsigned p = __builtin_nontemporal_load(&pairs[gbase + i]);
        int r = atomicAdd(&ofs[p & (BSZ - 1)], 1);
        sp[r] = p;
    }
    __syncthreads();
}

__device__ inline void emit_stats(float sum0, float sq0, float mn0, float mx0,
                                  float sum1, float sq1, float mn1, float mx1,
                                  int dg, int n, int lane, int sub,
                                  ushort* __restrict__ tmpb, int* __restrict__ deg_out)
{
#pragma unroll
    for (int off = 16; off <= 32; off <<= 1) {
        sum0 += __shfl_xor(sum0, off); sq0 += __shfl_xor(sq0, off);
        mn0 = fminf(mn0, __shfl_xor(mn0, off)); mx0 = fmaxf(mx0, __shfl_xor(mx0, off));
        sum1 += __shfl_xor(sum1, off); sq1 += __shfl_xor(sq1, off);
        mn1 = fminf(mn1, __shfl_xor(mn1, off)); mx1 = fmaxf(mx1, __shfl_xor(mx1, off));
    }
    float safe = fmaxf((float)dg, 1.f);
    float r = 1.f / safe;
    bool has = dg > 0;
    float mean0 = sum0 * r, mean1 = sum1 * r;
    float sd0 = sqrtf(fmaxf(sq0 * r - mean0 * mean0, 0.f) + EPSF);
    float sd1 = sqrtf(fmaxf(sq1 * r - mean1 * mean1, 0.f) + EPSF);
    float v0 = (sub == 0) ? mean0 : (sub == 1) ? (has ? mn0 : 0.f)
             : (sub == 2) ? (has ? mx0 : 0.f) : sd0;
    float v1 = (sub == 0) ? mean1 : (sub == 1) ? (has ? mn1 : 0.f)
             : (sub == 2) ? (has ? mx1 : 0.f) : sd1;
    ushort* tp = tmpb + (size_t)n * 128;
    tp[lane] = (ushort)f2bf_rne(v0);
    tp[64 + lane] = (ushort)f2bf_rne(v1);
    if (lane == 0) deg_out[n] = dg;
}

// ---- gather from packed h; 512 threads = 8 waves/block; LDS deal ----------
__global__ __launch_bounds__(512) void agg_from_h3(
    const unsigned* __restrict__ h, const int* __restrict__ gcur,
    const unsigned* __restrict__ pairs,
    ushort* __restrict__ tmpb, int* __restrict__ deg_out, int Nd)
{
    __shared__ unsigned sp[BSZ * CAPW];    // 11264 B
    __shared__ int cnt[BSZ];
    int b = blockIdx.x, tid = threadIdx.x;
    int gbase = b * BCAP;
    int ecnt = gcur[b] - gbase;
    if (ecnt > BCAP) ecnt = BCAP;
    if (ecnt < 0) ecnt = 0;
    if (tid < BSZ) cnt[tid] = 0;
    __syncthreads();
    for (int i = tid; i < ecnt; i += 512) {
        unsigned p = __builtin_nontemporal_load(&pairs[gbase + i]);
        int dl = (int)(p & (BSZ - 1));
        int r = atomicAdd(&cnt[dl], 1);
        if (r < CAPW) sp[dl * CAPW + r] = p;   // per-dst cap: ~10 sigma guard
    }
    __syncthreads();

    int wv = tid >> 6, lane = tid & 63, sub = lane >> 4, d = lane & 15;
#pragma unroll 1
    for (int q = 0; q < 4; ++q) {
        int dl = wv * 4 + q;
        int n = b * BSZ + dl;
        if (n >= Nd) break;
        int dg = cnt[dl];
        int dgc = (dg < CAPW) ? dg : CAPW;
        const unsigned* swp = sp + dl * CAPW;
        float sum0 = 0.f, sq0 = 0.f, mn0 = INFINITY, mx0 = -INFINITY;
        float sum1 = 0.f, sq1 = 0.f, mn1 = INFINITY, mx1 = -INFINITY;
        int nt = (dgc + 31) >> 5;          // 32 edges per wave-iteration
        for (int t = 0; t < nt; ++t) {
            int base = t * 32 + sub;
            unsigned hv[8];
#pragma unroll
            for (int j = 0; j < 8; ++j) {   // 8 independent gathers in flight
                int e = base + j * 4;
                int ec = (e < dgc) ? e : (dgc - 1);
                unsigned p = swp[ec];
                hv[j] = h[(p >> 9) * 16 + d];
            }
#pragma unroll
            for (int j = 0; j < 8; ++j) {
                int e = base + j * 4;
                if (e < dgc) {
                    float me = bf2f_lo(hv[j]);
                    float vm = bf2f_hi(hv[j]);
                    sum0 += me; sq0 += me * me;
                    mn0 = fminf(mn0, me); mx0 = fmaxf(mx0, me);
                    sum1 += vm; sq1 += vm * vm;
                    mn1 = fminf(mn1, vm); mx1 = fmaxf(mx1, vm);
                }
            }
        }
        emit_stats(sum0, sq0, mn0, mx0, sum1, sq1, mn1, mx1,
                   dg, n, lane, sub, tmpb, deg_out);
    }
}

// ---- fallback: gather w per edge (bf16 table if use_bf, else fp32) --------
__global__ __launch_bounds__(256) void agg_from_w(
    const int* __restrict__ Cat_src, const float* __restrict__ w,
    const ushort* __restrict__ wb, int use_bf, const int* __restrict__ gcur,
    const unsigned* __restrict__ pairs,
    ushort* __restrict__ tmpb, int* __restrict__ deg_out, int Nd)
{
    __shared__ unsigned sp[BCAP];
    __shared__ int hist[BSZ];
    __shared__ int ofs[BSZ];
    __shared__ int start[BSZ];
    int b = blockIdx.x, tid = threadIdx.x;
    int gbase = b * BCAP;
    int cnt = gcur[b] - gbase;
    if (cnt > BCAP) cnt = BCAP;
    if (cnt < 0) cnt = 0;
    bucket_sort(pairs, gbase, cnt, sp, hist, ofs, start, tid);

    int wv = tid >> 6, lane = tid & 63, sub = lane >> 4, d = lane & 15;
#pragma unroll 1
    for (int q = 0; q < 8; ++q) {
        int dl = wv * 8 + q;
        int n = b * BSZ + dl;
        if (n >= Nd) break;
        int st = start[dl], dg = hist[dl];
        float sum0 = 0.f, sq0 = 0.f, mn0 = INFINITY, mx0 = -INFINITY;
        float sum1 = 0.f, sq1 = 0.f, mn1 = INFINITY, mx1 = -INFINITY;
        int nt = (dg + 3) >> 2;
        for (int t = 0; t < nt; ++t) {
            int e4 = t * 4 + sub;
            int ec = (e4 < dg) ? e4 : (dg - 1);
            unsigned p = sp[st + ec];
            int src = (int)(p >> 9);
            int cat = Cat_src[src * 4 + (d & 3)];
            float vs = 0.f, vm = -INFINITY;
            if (use_bf) {
#pragma unroll
                for (int f = 0; f < 4; ++f) {
                    int id = __shfl(cat, sub * 16 + f, 64);
                    float a = bf2f_s(wb[id * 16 + d]);
                    vs += a; vm = fmaxf(vm, a);
                }
            } else {
#pragma unroll
                for (int f = 0; f < 4; ++f) {
                    int id = __shfl(cat, sub * 16 + f, 64);
                    float a = w[id * 16 + d];
                    vs += a; vm = fmaxf(vm, a);
                }
            }
            if (e4 < dg) {
                float me = vs * 0.25f;
                sum0 += me; sq0 += me * me;
                mn0 = fminf(mn0, me); mx0 = fmaxf(mx0, me);
                sum1 += vm; sq1 += vm * vm;
                mn1 = fminf(mn1, vm); mx1 = fmaxf(mx1, vm);
            }
        }
        emit_stats(sum0, sq0, mn0, mx0, sum1, sq1, mn1, mx1,
                   dg, n, lane, sub, tmpb, deg_out);
    }
}

// ---------------- finalize via MFMA, packed weights, bf16 X buffer ---------
// Layouts (gfx950, verified): A[m=lane&15][k=(lane>>4)*8+j];
// B[k][n=lane&15]; C/D col=lane&15, row=(lane>>4)*4+reg.
__global__ __launch_bounds__(256) void finalize_mfma(
    const int* __restrict__ Cat_dst, const int* __restrict__ label,
    const float* __restrict__ w, const ushort* __restrict__ wpack,
    const float* __restrict__ b_agg,
    const float* __restrict__ w_lin, const float* __restrict__ b_lin,
    const float* __restrict__ b1, const float* __restrict__ b2,
    const float* __restrict__ W3, const float* __restrict__ b3,
    const int* __restrict__ deg_arr, const ushort* __restrict__ tmpb,
    float* __restrict__ out, int Nd)
{
    __shared__ __align__(16) ushort sx[4][16 * XPADS2];  // x, bf16
    __shared__ __align__(16) ushort sx2[4][16 * X2PADS]; // h1, bf16
    __shared__ float sdeep[4][16];

    int tid = threadIdx.x;
    int wv = tid >> 6, lane = tid & 63;
    int q = lane >> 4, m = lane & 15;
    int n0 = (blockIdx.x * 4 + wv) * 16;
    int n = n0 + m;
    int nc = (n < Nd) ? n : (Nd - 1);

    ushort* X = sx[wv];
    ushort* X2 = sx2[wv];

    float fdeg = (float)deg_arr[nc];
    float logd = logf(fdeg + 1.f);
    const float logavg = logf(33.0f);
    float amp = logd / logavg;
    float att = (logd > 0.f) ? (logavg / fmaxf(logd, EPSF)) : 0.f;
    float ampr[4], attr[4];
#pragma unroll
    for (int r = 0; r < 4; ++r) {
        ampr[r] = __shfl(amp, q * 4 + r, 64);
        attr[r] = __shfl(att, q * 4 + r, 64);
    }

    // Phase A: mes = scaled @ W_agg + b_agg, scalers folded post-MFMA
    const ushort* tpn = tmpb + (size_t)nc * 128;
#pragma unroll
    for (int kvar = 0; kvar < 2; ++kvar) {
        short8 af0 = *(const short8*)(tpn + kvar * 64 + q * 8);
        short8 af1 = *(const short8*)(tpn + kvar * 64 + 32 + q * 8);
        float4v aI = {0.f,0.f,0.f,0.f}, aA = {0.f,0.f,0.f,0.f}, aT = {0.f,0.f,0.f,0.f};
#pragma unroll
        for (int sb = 0; sb < 3; ++sb) {
            short8 b0 = *(const short8*)(wpack +
                (size_t)(((kvar * 6 + sb * 2) * 4 + q) * 16 + m) * 8);
            short8 b1v = *(const short8*)(wpack +
                (size_t)(((kvar * 6 + sb * 2 + 1) * 4 + q) * 16 + m) * 8);
            if (sb == 0) {
                aI = __builtin_amdgcn_mfma_f32_16x16x32_bf16(af0, b0, aI, 0, 0, 0);
                aI = __builtin_amdgcn_mfma_f32_16x16x32_bf16(af1, b1v, aI, 0, 0, 0);
            } else if (sb == 1) {
                aA = __builtin_amdgcn_mfma_f32_16x16x32_bf16(af0, b0, aA, 0, 0, 0);
                aA = __builtin_amdgcn_mfma_f32_16x16x32_bf16(af1, b1v, aA, 0, 0, 0);
            } else {
                aT = __builtin_amdgcn_mfma_f32_16x16x32_bf16(af0, b0, aT, 0, 0, 0);
                aT = __builtin_amdgcn_mfma_f32_16x16x32_bf16(af1, b1v, aT, 0, 0, 0);
            }
        }
        float bias = b_agg[kvar * 16 + m];
#pragma unroll
        for (int r = 0; r < 4; ++r)
            X[(q * 4 + r) * XPADS2 + 64 + kvar * 16 + m] = (ushort)f2bf_rne(
                aI[r] + ampr[r] * aA[r] + attr[r] * aT[r] + bias);
    }
    // Phase B: dst cat embeddings -> X cols 0..63 (bf16)
    {
        int nl = lane >> 2, fl = lane & 3;
        int nn = n0 + nl;
        int nnc = (nn < Nd) ? nn : (Nd - 1);
        int cid = Cat_dst[nnc * 4 + fl];
        const float4* R = (const float4*)(w + (size_t)cid * 16);
        float4 r0 = R[0], r1 = R[1], r2 = R[2], r3 = R[3];
        short8 o0, o1;
        o0[0] = bf16_of(r0.x); o0[1] = bf16_of(r0.y);
        o0[2] = bf16_of(r0.z); o0[3] = bf16_of(r0.w);
        o0[4] = bf16_of(r1.x); o0[5] = bf16_of(r1.y);
        o0[6] = bf16_of(r1.z); o0[7] = bf16_of(r1.w);
        o1[0] = bf16_of(r2.x); o1[1] = bf16_of(r2.y);
        o1[2] = bf16_of(r2.z); o1[3] = bf16_of(r2.w);
        o1[4] = bf16_of(r3.x); o1[5] = bf16_of(r3.y);
        o1[6] = bf16_of(r3.z); o1[7] = bf16_of(r3.w);
        ushort* xp = X + nl * XPADS2 + fl * 16;
        *(short8*)(xp) = o0;
        *(short8*)(xp + 8) = o1;
    }
    __syncthreads();

    // Phase D: lin / FM stats for node m (q splits the 6 fields)
    float lin = 0.f, sq = 0.f;
    float sd[16];
#pragma unroll
    for (int u = 0; u < 16; ++u) sd[u] = 0.f;
    {
        const ushort* xp = X + m * XPADS2 + q * 16;
        const float* wl = w_lin + q * 16;
#pragma unroll
        for (int u = 0; u < 16; ++u) {
            float v = bf2f_s(xp[u]);
            lin += v * wl[u]; sq += v * v; sd[u] += v;
        }
    }
    if (q < 2) {
        const ushort* xp = X + m * XPADS2 + (4 + q) * 16;
        const float* wl = w_lin + (4 + q) * 16;
#pragma unroll
        for (int u = 0; u < 16; ++u) {
            float v = bf2f_s(xp[u]);
            lin += v * wl[u]; sq += v * v; sd[u] += v;
        }
    }
#pragma unroll
    for (int off = 16; off <= 32; off <<= 1) {
        lin += __shfl_xor(lin, off);
        sq  += __shfl_xor(sq, off);
#pragma unroll
        for (int u = 0; u < 16; ++u) sd[u] += __shfl_xor(sd[u], off);
    }
    float fm = 0.f;
#pragma unroll
    for (int u = 0; u < 16; ++u) fm += sd[u] * sd[u];
    fm = 0.5f * (fm - sq);

    // Phase E: h1 = relu(x @ W1 + b1), A-frags direct from bf16 X
    short8 xa[3];
#pragma unroll
    for (int t = 0; t < 3; ++t)
        xa[t] = *(const short8*)(X + m * XPADS2 + t * 32 + q * 8);
#pragma unroll
    for (int nt = 0; nt < 4; ++nt) {
        float4v acc = {0.f, 0.f, 0.f, 0.f};
#pragma unroll
        for (int t = 0; t < 3; ++t) {
            short8 bf = *(const short8*)(wpack + 6144 +
                (size_t)((t * 4 + q) * 64 + nt * 16 + m) * 8);
            acc = __builtin_amdgcn_mfma_f32_16x16x32_bf16(xa[t], bf, acc, 0, 0, 0);
        }
        float bb = b1[nt * 16 + m];
#pragma unroll
        for (int r = 0; r < 4; ++r)
            X2[(q * 4 + r) * X2PADS + nt * 16 + m] =
                (ushort)f2bf_rne(fmaxf(acc[r] + bb, 0.f));
    }
    __syncthreads();

    // Phase F: h2 = relu(h1 @ W2 + b2); deep = h2 @ W3
    short8 ha[2];
#pragma unroll
    for (int t = 0; t < 2; ++t)
        ha[t] = *(const short8*)(X2 + m * X2PADS + t * 32 + q * 8);
    float dp[4] = {0.f, 0.f, 0.f, 0.f};
#pragma unroll
    for (int nt = 0; nt < 2; ++nt) {
        float4v acc = {0.f, 0.f, 0.f, 0.f};
#pragma unroll
        for (int t = 0; t < 2; ++t) {
            short8 bf = *(const short8*)(wpack + 12288 +
                (size_t)((t * 4 + q) * 32 + nt * 16 + m) * 8);
            acc = __builtin_amdgcn_mfma_f32_16x16x32_bf16(ha[t], bf, acc, 0, 0, 0);
        }
        float bb = b2[nt * 16 + m];
        float w3 = W3[nt * 16 + m];
#pragma unroll
        for (int r = 0; r < 4; ++r)
            dp[r] += fmaxf(acc[r] + bb, 0.f) * w3;
    }
#pragma unroll
    for (int off = 1; off <= 8; off <<= 1) {
#pragma unroll
        for (int r = 0; r < 4; ++r) dp[r] += __shfl_xor(dp[r], off);
    }
    if (m < 4)
        sdeep[wv][q * 4 + m] = (m == 0) ? dp[0] : (m == 1) ? dp[1]
                             : (m == 2) ? dp[2] : dp[3];
    __syncthreads();
    float deep = sdeep[wv][m];

    if (q == 0 && n < Nd) {
        float z = lin + b_lin[0] + fm + deep + b3[0];
        float pred = 1.f / (1.f + expf(-z));
        out[n] = pred;
        out[Nd + n] = (float)label[n];
    }
}

extern "C" void kernel_launch(void* const* d_in, const int* in_sizes, int n_in,
                              void* d_out, int out_size, void* d_ws, size_t ws_size,
                              hipStream_t stream) {
    const int*   Cat_src = (const int*)d_in[0];
    const int*   Cat_dst = (const int*)d_in[1];
    const int*   src_ids = (const int*)d_in[2];
    const int*   dst_ids = (const int*)d_in[3];
    const int*   label   = (const int*)d_in[4];
    const float* w       = (const float*)d_in[5];
    const float* W_agg   = (const float*)d_in[6];
    const float* b_agg   = (const float*)d_in[7];
    const float* w_lin   = (const float*)d_in[8];
    const float* b_lin   = (const float*)d_in[9];
    const float* W1      = (const float*)d_in[10];
    const float* b1      = (const float*)d_in[11];
    const float* W2      = (const float*)d_in[12];
    const float* b2      = (const float*)d_in[13];
    const float* W3      = (const float*)d_in[14];
    const float* b3      = (const float*)d_in[15];

    int E  = in_sizes[2];
    int Nd = in_sizes[4];
    int Ns = in_sizes[0] / 4;
    int VD = in_sizes[5];
    int nb  = (Nd + BSZ - 1) >> BSH;
    int nsb = (nb + 15) >> 4;

    // ws layout: sbcursor[8*MAXSB] | gcur[MAXB] | deg[Nd]
    //            | pairs1[nsb*SBCAP] | pairs2[nb*BCAP] | (align)
    //            | tmpb[Nd*128 us] | wpack[NPACK us] | w_bf16[VD us] | h[Ns*16]
    int* sbcursor = (int*)d_ws;
    int* gcur     = sbcursor + 8 * MAXSB;
    int* deg      = gcur + MAXB;
    unsigned* pairs1 = (unsigned*)(deg + Nd);
    unsigned* pairs2 = pairs1 + (size_t)nsb * SBCAP;
    size_t off_tmp = (((size_t)(8 * MAXSB + MAXB + Nd)
                      + (size_t)nsb * SBCAP + (size_t)nb * BCAP) * 4 + 255)
                     & ~(size_t)255;
    ushort* tmpb = (ushort*)((char*)d_ws + off_tmp);
    ushort* wpack = tmpb + (size_t)Nd * 128;
    ushort* w_bf16 = wpack + NPACK;
    unsigned* h  = (unsigned*)(w_bf16 + VD);

    size_t need_common = off_tmp + (size_t)Nd * 256 + (size_t)NPACK * 2;
    size_t need_A = need_common + (size_t)VD * 2;
    size_t need_B = need_A + (size_t)Ns * 64;
    int mode = (ws_size >= need_B) ? 2 : (ws_size >= need_A) ? 1 : 0;

    float* out = (float*)d_out;

    int nzc = (nb + 255) >> 8;
    int ncb = (mode >= 1) ? (VD / 4 + 255) / 256 : 0;
    hipLaunchKernelGGL(setup_all, dim3(nzc + 1 + ncb), dim3(256), 0, stream,
                       sbcursor, gcur, nb, nsb, W_agg, W1, W2, wpack,
                       w, w_bf16, VD, mode >= 1);
    int nscb = (E + TILE - 1) / TILE;
    int hb = (mode == 2) ? (Ns + 255) / 256 : 0;
    hipLaunchKernelGGL(sb_and_build, dim3(nscb + hb), dim3(256), 0, stream,
                       src_ids, dst_ids, sbcursor, pairs1, E, nsb, nscb,
                       Cat_src, w_bf16, h, Ns);
    hipLaunchKernelGGL(scatter_fine7, dim3(nsb * SEG), dim3(256), 0, stream,
                       pairs1, sbcursor, gcur, pairs2, nb, nsb);
    if (mode == 2) {
        hipLaunchKernelGGL(agg_from_h3, dim3(nb), dim3(512), 0, stream,
                           h, gcur, pairs2, tmpb, deg, Nd);
    } else {
        hipLaunchKernelGGL(agg_from_w, dim3(nb), dim3(256), 0, stream,
                           Cat_src, w, w_bf16, mode, gcur, pairs2,
                           tmpb, deg, Nd);
    }
    hipLaunchKernelGGL(finalize_mfma, dim3((Nd + 63) / 64), dim3(256), 0, stream,
                       Cat_dst, label, w, wpack, b_agg, w_lin, b_lin,
                       b1, b2, W3, b3, deg, tmpb, out, Nd);
}